// Round 1
// baseline (447813.379 us; speedup 1.0000x reference)
//
#include <hip/hip_runtime.h>
#include <math.h>

#define E 262144
#define Nn 16384
#define H 8
#define D 64
#define HD 512
#define HID 256

__device__ __forceinline__ float wave_sum(float v) {
    #pragma unroll
    for (int m = 1; m < 64; m <<= 1) v += __shfl_xor(v, m, 64);
    return v;
}

// v[h][j] = sum_d atten[h][d] * Wq[d][j]
__global__ void prep_v(const float* __restrict__ atten, const float* __restrict__ Wq,
                       float* __restrict__ v) {
    int t = threadIdx.x;            // 512 threads
    int h = t >> 6, j = t & 63;
    float a = 0.f;
    #pragma unroll 8
    for (int d = 0; d < 64; ++d) a += atten[h * 64 + d] * Wq[d * 64 + j];
    v[h * 64 + j] = a;
}

// fc1T[d][c] = fc1_w[c][d]  (64x256);  fc2T[c][d] = fc2_w[d][c]  (256x64)
__global__ void prep_fcT(const float* __restrict__ fc1w, const float* __restrict__ fc2w,
                         float* __restrict__ fc1T, float* __restrict__ fc2T) {
    int i = blockIdx.x * 256 + threadIdx.x;   // 32768 threads
    if (i < 16384) {
        int c = i >> 6, d = i & 63;
        fc1T[d * 256 + c] = fc1w[i];
    } else {
        int i2 = i - 16384;
        int dd = i2 >> 8, c = i2 & 255;
        fc2T[c * 64 + dd] = fc2w[i2];
    }
}

// k[e][d] = 0.125 * sum_j x[e][j] * Wk[d][j]
__global__ __launch_bounds__(256) void compute_k(const float* __restrict__ x,
                                                 const float* __restrict__ Wk,
                                                 float* __restrict__ kbuf) {
    __shared__ float sWk[64][130];
    int t = threadIdx.x;
    for (int i = t; i < 64 * 128; i += 256) sWk[i >> 7][i & 127] = Wk[i];
    __syncthreads();
    int lane = t & 63, w = t >> 6;
    for (int e = blockIdx.x * 4 + w; e < E; e += gridDim.x * 4) {
        const float* xr = x + (size_t)e * 128;
        float acc = 0.f;
        #pragma unroll 8
        for (int j = 0; j < 128; ++j) acc += xr[j] * sWk[lane][j];
        kbuf[(size_t)e * 64 + lane] = acc * 0.125f;
    }
}

// slots = mu + exp(log_sigma) * norm_dist
__global__ void init_slots(const float* __restrict__ nd, const float* __restrict__ mu,
                           const float* __restrict__ lsig, float* __restrict__ out) {
    __shared__ float sMu[64], sSig[64];
    if (threadIdx.x < 64) {
        sMu[threadIdx.x]  = mu[threadIdx.x];
        sSig[threadIdx.x] = __expf(lsig[threadIdx.x]);
    }
    __syncthreads();
    size_t n4 = (size_t)E * HD / 4;
    size_t stride = (size_t)gridDim.x * blockDim.x;
    for (size_t i = (size_t)blockIdx.x * blockDim.x + threadIdx.x; i < n4; i += stride) {
        float4 v = ((const float4*)nd)[i];
        int d0 = (int)((i * 4) & 63);
        v.x = sMu[d0]     + sSig[d0]     * v.x;
        v.y = sMu[d0 + 1] + sSig[d0 + 1] * v.y;
        v.z = sMu[d0 + 2] + sSig[d0 + 2] * v.z;
        v.w = sMu[d0 + 3] + sSig[d0 + 3] * v.w;
        ((float4*)out)[i] = v;
    }
}

__global__ void seg_init(unsigned* __restrict__ segmax, float* __restrict__ segsum) {
    int i = blockIdx.x * 256 + threadIdx.x;
    if (i < Nn * H) { segmax[i] = 0u; segsum[i] = 0.f; }
}

// one wave per (e,h): LN(slots row) -> dot v_h -> leaky_relu -> alpha ; atomicMax into segmax
__global__ __launch_bounds__(256) void alpha_ln(const float* __restrict__ cur,
                                                const float* __restrict__ v,
                                                const float* __restrict__ lnw,
                                                const float* __restrict__ lnb,
                                                const int* __restrict__ eidx,
                                                float* __restrict__ alpha,
                                                unsigned* __restrict__ segmax) {
    int lane = threadIdx.x & 63, w = threadIdx.x >> 6;
    size_t p = (size_t)blockIdx.x * 4 + w;          // pair index, grid = E*H/4 exactly
    float x = cur[p * 64 + lane];
    float m = wave_sum(x) * (1.f / 64.f);
    float d = x - m;
    float var = wave_sum(d * d) * (1.f / 64.f);
    float rs = rsqrtf(var + 1e-5f);
    float ln = d * rs * lnw[lane] + lnb[lane];
    int h = (int)(p & 7);
    float dot = wave_sum(ln * v[h * 64 + lane]) * 0.125f;
    float a = dot >= 0.f ? dot : 0.2f * dot;
    if (lane == 0) {
        alpha[p] = a;
        int e = (int)(p >> 3);
        int id = eidx[e];
        unsigned b = __float_as_uint(a);
        unsigned enc = (b & 0x80000000u) ? ~b : (b | 0x80000000u);
        atomicMax(&segmax[id * 8 + h], enc);
    }
}

__global__ void exp_sum(const int* __restrict__ eidx, const unsigned* __restrict__ segmax,
                        float* __restrict__ alpha, float* __restrict__ segsum) {
    size_t p = (size_t)blockIdx.x * 256 + threadIdx.x;
    int e = (int)(p >> 3), h = (int)(p & 7);
    int id = eidx[e];
    unsigned u = segmax[id * 8 + h];
    float m = __uint_as_float((u & 0x80000000u) ? (u & 0x7fffffffu) : ~u);
    float val = __expf(alpha[p] - m);
    alpha[p] = val;
    atomicAdd(&segsum[id * 8 + h], val);
}

__global__ void norm_alpha(const int* __restrict__ eidx, const float* __restrict__ segsum,
                           float* __restrict__ alpha) {
    size_t p = (size_t)blockIdx.x * 256 + threadIdx.x;
    int e = (int)(p >> 3), h = (int)(p & 7);
    alpha[p] = alpha[p] / (segsum[eidx[e] * 8 + h] + 1e-16f);
}

// Fused GRU: block = 64 edges x 64 output cols (head cb). 6 accum planes:
// 0..2 = updates @ w_ih rows {c, c+512, c+1024}; 3..5 = hprev @ w_hh rows same.
__global__ __launch_bounds__(256, 2) void gru(const float* __restrict__ cur,
                                              const float* __restrict__ kbuf,
                                              const float* __restrict__ alpha,
                                              const float* __restrict__ w_ih,
                                              const float* __restrict__ w_hh,
                                              const float* __restrict__ b_ih,
                                              const float* __restrict__ b_hh,
                                              float* __restrict__ nxt) {
    __shared__ float sA[2][64][20];   // [u/h][edge][k] pad->20
    __shared__ float sW[6][64][20];   // [mat][col][k]
    int cb = blockIdx.x & 7;
    int e0 = (blockIdx.x >> 3) * 64;
    int t = threadIdx.x;
    int lo4 = t & 15, hi4 = t >> 4;

    float acc[6][4][4];
    #pragma unroll
    for (int m = 0; m < 6; ++m)
        #pragma unroll
        for (int i = 0; i < 4; ++i)
            #pragma unroll
            for (int j = 0; j < 4; ++j) acc[m][i][j] = 0.f;

    for (int k0 = 0; k0 < 512; k0 += 16) {
        __syncthreads();
        // stage A tiles: updates (k*alpha) and hprev
        int kh = k0 >> 6, kd0 = k0 & 63;
        #pragma unroll
        for (int pp = 0; pp < 4; ++pp) {
            int e = hi4 + 16 * pp;
            size_t ge = (size_t)(e0 + e);
            float an = alpha[ge * 8 + kh];
            sA[0][e][lo4] = kbuf[ge * 64 + kd0 + lo4] * an;
            sA[1][e][lo4] = cur[ge * 512 + k0 + lo4];
        }
        // stage W tiles
        #pragma unroll
        for (int m = 0; m < 6; ++m) {
            const float* wm = (m < 3) ? w_ih : w_hh;
            int rbase = (m % 3) * 512 + cb * 64;
            #pragma unroll
            for (int jj = 0; jj < 4; ++jj) {
                int o = hi4 + 16 * jj;
                sW[m][o][lo4] = wm[(size_t)(rbase + o) * 512 + k0 + lo4];
            }
        }
        __syncthreads();
        // compute
        #pragma unroll
        for (int kq = 0; kq < 4; ++kq) {
            float4 au[4], ah[4];
            #pragma unroll
            for (int i = 0; i < 4; ++i) {
                au[i] = *(const float4*)&sA[0][hi4 + 16 * i][kq * 4];
                ah[i] = *(const float4*)&sA[1][hi4 + 16 * i][kq * 4];
            }
            #pragma unroll
            for (int j = 0; j < 4; ++j) {
                int c = lo4 + 16 * j;
                #pragma unroll
                for (int m = 0; m < 3; ++m) {
                    float4 wv = *(const float4*)&sW[m][c][kq * 4];
                    #pragma unroll
                    for (int i = 0; i < 4; ++i)
                        acc[m][i][j] += au[i].x * wv.x + au[i].y * wv.y +
                                        au[i].z * wv.z + au[i].w * wv.w;
                }
                #pragma unroll
                for (int m = 3; m < 6; ++m) {
                    float4 wv = *(const float4*)&sW[m][c][kq * 4];
                    #pragma unroll
                    for (int i = 0; i < 4; ++i)
                        acc[m][i][j] += ah[i].x * wv.x + ah[i].y * wv.y +
                                        ah[i].z * wv.z + ah[i].w * wv.w;
                }
            }
        }
    }
    // epilogue: gates + write new slots
    #pragma unroll
    for (int i = 0; i < 4; ++i) {
        size_t ge = (size_t)(e0 + hi4 + 16 * i);
        #pragma unroll
        for (int j = 0; j < 4; ++j) {
            int c = cb * 64 + lo4 + 16 * j;
            float r = 1.f / (1.f + __expf(-(acc[0][i][j] + acc[3][i][j] + b_ih[c] + b_hh[c])));
            float z = 1.f / (1.f + __expf(-(acc[1][i][j] + acc[4][i][j] + b_ih[c + 512] + b_hh[c + 512])));
            float n = tanhf(acc[2][i][j] + b_ih[c + 1024] + r * (acc[5][i][j] + b_hh[c + 1024]));
            float hprev = cur[ge * 512 + c];
            nxt[ge * 512 + c] = (1.f - z) * n + z * hprev;
        }
    }
}

// MLP + residual, in-place per (e,h) row. one wave per row.
__global__ __launch_bounds__(256) void mlp(float* __restrict__ slots,
                                           const float* __restrict__ lnw,
                                           const float* __restrict__ lnb,
                                           const float* __restrict__ fc1T,
                                           const float* __restrict__ fc1b,
                                           const float* __restrict__ fc2T,
                                           const float* __restrict__ fc2b) {
    __shared__ float sLn[4][64];
    __shared__ float sY1[4][256];
    int lane = threadIdx.x & 63, w = threadIdx.x >> 6;
    size_t row = (size_t)blockIdx.x * 4 + w;     // grid = E*H/4 exactly
    float* base = slots + row * 64;
    float x = base[lane];
    float m = wave_sum(x) * (1.f / 64.f);
    float d = x - m;
    float var = wave_sum(d * d) * (1.f / 64.f);
    float ln = d * rsqrtf(var + 1e-5f) * lnw[lane] + lnb[lane];
    sLn[w][lane] = ln;
    __syncthreads();
    float y[4];
    #pragma unroll
    for (int j = 0; j < 4; ++j) y[j] = fc1b[lane + 64 * j];
    #pragma unroll 4
    for (int dd = 0; dd < 64; ++dd) {
        float vv = sLn[w][dd];
        const float* r = fc1T + dd * 256;
        #pragma unroll
        for (int j = 0; j < 4; ++j) y[j] += vv * r[lane + 64 * j];
    }
    #pragma unroll
    for (int j = 0; j < 4; ++j) sY1[w][lane + 64 * j] = fmaxf(y[j], 0.f);
    __syncthreads();
    float a2 = fc2b[lane];
    #pragma unroll 4
    for (int c = 0; c < 256; ++c) a2 += sY1[w][c] * fc2T[c * 64 + lane];
    base[lane] = x + a2;
}

extern "C" void kernel_launch(void* const* d_in, const int* in_sizes, int n_in,
                              void* d_out, int out_size, void* d_ws, size_t ws_size,
                              hipStream_t stream) {
    const float* x     = (const float*)d_in[0];
    const int*   eidx  = (const int*)d_in[1];
    const float* nd    = (const float*)d_in[3];
    const float* mu    = (const float*)d_in[4];
    const float* lsig  = (const float*)d_in[5];
    const float* atten = (const float*)d_in[6];
    const float* ln_sw = (const float*)d_in[7];
    const float* ln_sb = (const float*)d_in[8];
    const float* ln_mw = (const float*)d_in[9];
    const float* ln_mb = (const float*)d_in[10];
    const float* Wq    = (const float*)d_in[11];
    const float* Wk    = (const float*)d_in[12];
    const float* w_ih  = (const float*)d_in[13];
    const float* w_hh  = (const float*)d_in[14];
    const float* b_ih  = (const float*)d_in[15];
    const float* b_hh  = (const float*)d_in[16];
    const float* fc1w  = (const float*)d_in[17];
    const float* fc1b  = (const float*)d_in[18];
    const float* fc2w  = (const float*)d_in[19];
    const float* fc2b  = (const float*)d_in[20];

    float* out = (float*)d_out;
    char* ws = (char*)d_ws;
    size_t off = 0;
    auto alloc = [&](size_t nbytes) {
        void* p = ws + off;
        off += (nbytes + 255) & ~(size_t)255;
        return p;
    };
    float*    slotsA = (float*)alloc((size_t)E * HD * 4);
    float*    kbuf   = (float*)alloc((size_t)E * 64 * 4);
    float*    alpha  = (float*)alloc((size_t)E * 8 * 4);
    unsigned* segmax = (unsigned*)alloc((size_t)Nn * 8 * 4);
    float*    segsum = (float*)alloc((size_t)Nn * 8 * 4);
    float*    vbuf   = (float*)alloc(512 * 4);
    float*    fc1T   = (float*)alloc(16384 * 4);
    float*    fc2T   = (float*)alloc(16384 * 4);

    prep_v<<<1, 512, 0, stream>>>(atten, Wq, vbuf);
    prep_fcT<<<128, 256, 0, stream>>>(fc1w, fc2w, fc1T, fc2T);
    compute_k<<<4096, 256, 0, stream>>>(x, Wk, kbuf);
    init_slots<<<2048, 256, 0, stream>>>(nd, mu, lsig, slotsA);

    float* cur = slotsA;
    float* nxt = out;
    for (int it = 0; it < 3; ++it) {
        seg_init<<<512, 256, 0, stream>>>(segmax, segsum);
        alpha_ln<<<E * 8 / 4, 256, 0, stream>>>(cur, vbuf, ln_sw, ln_sb, eidx, alpha, segmax);
        exp_sum<<<E * 8 / 256, 256, 0, stream>>>(eidx, segmax, alpha, segsum);
        norm_alpha<<<E * 8 / 256, 256, 0, stream>>>(eidx, segsum, alpha);
        gru<<<(E / 64) * 8, 256, 0, stream>>>(cur, kbuf, alpha, w_ih, w_hh, b_ih, b_hh, nxt);
        mlp<<<E * 8 / 4, 256, 0, stream>>>(nxt, ln_mw, ln_mb, fc1T, fc1b, fc2T, fc2b);
        float* tmp = cur; cur = nxt; nxt = tmp;
    }
    (void)in_sizes; (void)n_in; (void)out_size; (void)ws_size;
}

// Round 2
// 30755.450 us; speedup vs baseline: 14.5605x; 14.5605x over previous
//
#include <hip/hip_runtime.h>
#include <math.h>

#define E 262144
#define Nn 16384
#define H 8
#define D 64
#define HD 512
#define HID 256

typedef float f32x4 __attribute__((ext_vector_type(4)));
typedef short bf16x8 __attribute__((ext_vector_type(8)));

__device__ __forceinline__ float wave_sum(float v) {
    #pragma unroll
    for (int m = 1; m < 64; m <<= 1) v += __shfl_xor(v, m, 64);
    return v;
}

__device__ __forceinline__ unsigned short f2bf(float f) {
    unsigned u = __float_as_uint(f);
    return (unsigned short)((u + 0x7fffu + ((u >> 16) & 1u)) >> 16);
}

// v[h][j] = sum_d atten[h][d] * Wq[d][j]
__global__ void prep_v(const float* __restrict__ atten, const float* __restrict__ Wq,
                       float* __restrict__ v) {
    int t = threadIdx.x;            // 512 threads
    int h = t >> 6, j = t & 63;
    float a = 0.f;
    #pragma unroll 8
    for (int d = 0; d < 64; ++d) a += atten[h * 64 + d] * Wq[d * 64 + j];
    v[h * 64 + j] = a;
}

// fc1T[d][c] = fc1_w[c][d]  (64x256);  fc2T[c][d] = fc2_w[d][c]  (256x64)
__global__ void prep_fcT(const float* __restrict__ fc1w, const float* __restrict__ fc2w,
                         float* __restrict__ fc1T, float* __restrict__ fc2T) {
    int i = blockIdx.x * 256 + threadIdx.x;   // 32768 threads
    if (i < 16384) {
        int c = i >> 6, d = i & 63;
        fc1T[d * 256 + c] = fc1w[i];
    } else {
        int i2 = i - 16384;
        int dd = i2 >> 8, c = i2 & 255;
        fc2T[c * 64 + dd] = fc2w[i2];
    }
}

// Pre-swizzle GRU weights to bf16 in the exact per-kstep LDS image:
// wb[cb][t][m][kg][c][j]  (cb: 8 col-blocks, t: 16 ksteps, m: 6 mats,
// kg: 4 k-groups of 8, c: 64 cols, j: 8 k within group)
__global__ void wprep(const float* __restrict__ w_ih, const float* __restrict__ w_hh,
                      unsigned short* __restrict__ wb) {
    int o = blockIdx.x * 256 + threadIdx.x;   // 3,145,728 total
    int blk = o / 12288;
    int w = o - blk * 12288;
    int j = w & 7, c = (w >> 3) & 63, mk = w >> 9;
    int kg = mk & 3, m = mk >> 2;
    int t = blk & 15, cb = blk >> 4;
    const float* wm = (m < 3) ? w_ih : w_hh;
    int row = (m % 3) * 512 + cb * 64 + c;
    int k = t * 32 + kg * 8 + j;
    wb[o] = f2bf(wm[(size_t)row * 512 + k]);
}

// k[e][d] = 0.125 * sum_j x[e][j] * Wk[d][j]
__global__ __launch_bounds__(256) void compute_k(const float* __restrict__ x,
                                                 const float* __restrict__ Wk,
                                                 float* __restrict__ kbuf) {
    __shared__ float sWk[64][130];
    int t = threadIdx.x;
    for (int i = t; i < 64 * 128; i += 256) sWk[i >> 7][i & 127] = Wk[i];
    __syncthreads();
    int lane = t & 63, w = t >> 6;
    for (int e = blockIdx.x * 4 + w; e < E; e += gridDim.x * 4) {
        const float* xr = x + (size_t)e * 128;
        float acc = 0.f;
        #pragma unroll 8
        for (int j = 0; j < 128; ++j) acc += xr[j] * sWk[lane][j];
        kbuf[(size_t)e * 64 + lane] = acc * 0.125f;
    }
}

// slots = mu + exp(log_sigma) * norm_dist
__global__ void init_slots(const float* __restrict__ nd, const float* __restrict__ mu,
                           const float* __restrict__ lsig, float* __restrict__ out) {
    __shared__ float sMu[64], sSig[64];
    if (threadIdx.x < 64) {
        sMu[threadIdx.x]  = mu[threadIdx.x];
        sSig[threadIdx.x] = __expf(lsig[threadIdx.x]);
    }
    __syncthreads();
    size_t n4 = (size_t)E * HD / 4;
    size_t stride = (size_t)gridDim.x * blockDim.x;
    for (size_t i = (size_t)blockIdx.x * blockDim.x + threadIdx.x; i < n4; i += stride) {
        float4 v = ((const float4*)nd)[i];
        int d0 = (int)((i * 4) & 63);
        v.x = sMu[d0]     + sSig[d0]     * v.x;
        v.y = sMu[d0 + 1] + sSig[d0 + 1] * v.y;
        v.z = sMu[d0 + 2] + sSig[d0 + 2] * v.z;
        v.w = sMu[d0 + 3] + sSig[d0 + 3] * v.w;
        ((float4*)out)[i] = v;
    }
}

__global__ void seg_init(unsigned* __restrict__ segmax, float* __restrict__ segsum) {
    int i = blockIdx.x * 256 + threadIdx.x;
    if (i < Nn * H) { segmax[i] = 0u; segsum[i] = 0.f; }
}

// one wave per (e,h): LN(slots row) -> dot v_h -> leaky_relu -> alpha ; atomicMax into segmax
__global__ __launch_bounds__(256) void alpha_ln(const float* __restrict__ cur,
                                                const float* __restrict__ v,
                                                const float* __restrict__ lnw,
                                                const float* __restrict__ lnb,
                                                const int* __restrict__ eidx,
                                                float* __restrict__ alpha,
                                                unsigned* __restrict__ segmax) {
    int lane = threadIdx.x & 63, w = threadIdx.x >> 6;
    size_t p = (size_t)blockIdx.x * 4 + w;          // grid = E*H/4 exactly
    float x = cur[p * 64 + lane];
    float m = wave_sum(x) * (1.f / 64.f);
    float d = x - m;
    float var = wave_sum(d * d) * (1.f / 64.f);
    float rs = rsqrtf(var + 1e-5f);
    float ln = d * rs * lnw[lane] + lnb[lane];
    int h = (int)(p & 7);
    float dot = wave_sum(ln * v[h * 64 + lane]) * 0.125f;
    float a = dot >= 0.f ? dot : 0.2f * dot;
    if (lane == 0) {
        alpha[p] = a;
        int e = (int)(p >> 3);
        int id = eidx[e];
        unsigned b = __float_as_uint(a);
        unsigned enc = (b & 0x80000000u) ? ~b : (b | 0x80000000u);
        atomicMax(&segmax[id * 8 + h], enc);
    }
}

__global__ void exp_sum(const int* __restrict__ eidx, const unsigned* __restrict__ segmax,
                        float* __restrict__ alpha, float* __restrict__ segsum) {
    size_t p = (size_t)blockIdx.x * 256 + threadIdx.x;
    int e = (int)(p >> 3), h = (int)(p & 7);
    int id = eidx[e];
    unsigned u = segmax[id * 8 + h];
    float m = __uint_as_float((u & 0x80000000u) ? (u & 0x7fffffffu) : ~u);
    float val = __expf(alpha[p] - m);
    alpha[p] = val;
    atomicAdd(&segsum[id * 8 + h], val);
}

__global__ void norm_alpha(const int* __restrict__ eidx, const float* __restrict__ segsum,
                           float* __restrict__ alpha) {
    size_t p = (size_t)blockIdx.x * 256 + threadIdx.x;
    int e = (int)(p >> 3), h = (int)(p & 7);
    alpha[p] = alpha[p] / (segsum[eidx[e] * 8 + h] + 1e-16f);
}

// ---------------- MFMA GRU ----------------
// Block: 64 edges x 64 cols (col-block cb of 8). 4 waves in 2x2 (wave = 32e x 32c).
// 4 accumulation planes per wave: P0 = r-gate preact (u@ihr + h@hhr),
// P1 = z preact, P2 = i_n (u@ihn), P3 = h_n (h@hhn). f32 epilogue.
__global__ __launch_bounds__(256, 2) void gru_mfma(
    const float* __restrict__ cur, const float* __restrict__ kbuf,
    const float* __restrict__ alpha, const unsigned short* __restrict__ wb,
    const float* __restrict__ b_ih, const float* __restrict__ b_hh,
    float* __restrict__ nxt) {

    __shared__ unsigned short Au[2048];   // [kg][e 0..63][8]  (XOR-swizzled)
    __shared__ unsigned short Ah[2048];
    __shared__ unsigned short Bl[12288];  // [m 0..5][kg][c 0..63][8] = wb image

    int bid = blockIdx.x;
    int lbid = (bid & 7) * 4096 + (bid >> 3);   // XCD-contiguous chunks
    int eb = lbid >> 3, cb = lbid & 7;
    int e0 = eb * 64;

    int t = threadIdx.x;
    int lane = t & 63, wid = t >> 6;
    int wr = wid >> 1, wc = wid & 1;
    int EB = wr * 32, CB0 = wc * 32;
    int kg = lane >> 4, li = lane & 15;

    int se = t & 63, skg = t >> 6;   // staging role: edge, k-group

    f32x4 acc[4][2][2] = {};   // [plane][fe][f]

    for (int k0 = 0; k0 < 512; k0 += 32) {
        __syncthreads();
        // ---- stage A (updates = kbuf*alpha, hprev = cur), f32 -> bf16 ----
        {
            size_t ge = (size_t)(e0 + se);
            float al = alpha[ge * 8 + (k0 >> 6)];
            const float* kb = kbuf + ge * 64 + (k0 & 63) + skg * 8;
            const float* hb = cur + ge * 512 + k0 + skg * 8;
            float4 ku0 = *(const float4*)kb, ku1 = *(const float4*)(kb + 4);
            float4 hh0 = *(const float4*)hb, hh1 = *(const float4*)(hb + 4);
            bf16x8 uv, hv;
            uv[0] = (short)f2bf(ku0.x * al); uv[1] = (short)f2bf(ku0.y * al);
            uv[2] = (short)f2bf(ku0.z * al); uv[3] = (short)f2bf(ku0.w * al);
            uv[4] = (short)f2bf(ku1.x * al); uv[5] = (short)f2bf(ku1.y * al);
            uv[6] = (short)f2bf(ku1.z * al); uv[7] = (short)f2bf(ku1.w * al);
            hv[0] = (short)f2bf(hh0.x); hv[1] = (short)f2bf(hh0.y);
            hv[2] = (short)f2bf(hh0.z); hv[3] = (short)f2bf(hh0.w);
            hv[4] = (short)f2bf(hh1.x); hv[5] = (short)f2bf(hh1.y);
            hv[6] = (short)f2bf(hh1.z); hv[7] = (short)f2bf(hh1.w);
            int ao = skg * 512 + ((se * 8) ^ (skg * 8));
            *(bf16x8*)(Au + ao) = uv;
            *(bf16x8*)(Ah + ao) = hv;
        }
        // ---- stage B: linear 24KB copy of pre-swizzled weights ----
        {
            const float4* src = (const float4*)(wb + (size_t)(cb * 16 + (k0 >> 5)) * 12288);
            float4* dst = (float4*)Bl;
            #pragma unroll
            for (int q = 0; q < 6; ++q) dst[t + q * 256] = src[t + q * 256];
        }
        __syncthreads();

        // ---- fragments ----
        bf16x8 au0 = *(bf16x8*)(Au + kg * 512 + (((EB + li) * 8) ^ (kg * 8)));
        bf16x8 au1 = *(bf16x8*)(Au + kg * 512 + (((EB + 16 + li) * 8) ^ (kg * 8)));
        bf16x8 ah0 = *(bf16x8*)(Ah + kg * 512 + (((EB + li) * 8) ^ (kg * 8)));
        bf16x8 ah1 = *(bf16x8*)(Ah + kg * 512 + (((EB + 16 + li) * 8) ^ (kg * 8)));

        #pragma unroll
        for (int f = 0; f < 2; ++f) {
            int c8 = (CB0 + f * 16 + li) * 8;
            bf16x8 bir = *(bf16x8*)(Bl + (0 * 4 + kg) * 512 + c8);
            bf16x8 biz = *(bf16x8*)(Bl + (1 * 4 + kg) * 512 + c8);
            bf16x8 bin = *(bf16x8*)(Bl + (2 * 4 + kg) * 512 + c8);
            bf16x8 bhr = *(bf16x8*)(Bl + (3 * 4 + kg) * 512 + c8);
            bf16x8 bhz = *(bf16x8*)(Bl + (4 * 4 + kg) * 512 + c8);
            bf16x8 bhn = *(bf16x8*)(Bl + (5 * 4 + kg) * 512 + c8);

            acc[0][0][f] = __builtin_amdgcn_mfma_f32_16x16x32_bf16(au0, bir, acc[0][0][f], 0, 0, 0);
            acc[0][0][f] = __builtin_amdgcn_mfma_f32_16x16x32_bf16(ah0, bhr, acc[0][0][f], 0, 0, 0);
            acc[0][1][f] = __builtin_amdgcn_mfma_f32_16x16x32_bf16(au1, bir, acc[0][1][f], 0, 0, 0);
            acc[0][1][f] = __builtin_amdgcn_mfma_f32_16x16x32_bf16(ah1, bhr, acc[0][1][f], 0, 0, 0);

            acc[1][0][f] = __builtin_amdgcn_mfma_f32_16x16x32_bf16(au0, biz, acc[1][0][f], 0, 0, 0);
            acc[1][0][f] = __builtin_amdgcn_mfma_f32_16x16x32_bf16(ah0, bhz, acc[1][0][f], 0, 0, 0);
            acc[1][1][f] = __builtin_amdgcn_mfma_f32_16x16x32_bf16(au1, biz, acc[1][1][f], 0, 0, 0);
            acc[1][1][f] = __builtin_amdgcn_mfma_f32_16x16x32_bf16(ah1, bhz, acc[1][1][f], 0, 0, 0);

            acc[2][0][f] = __builtin_amdgcn_mfma_f32_16x16x32_bf16(au0, bin, acc[2][0][f], 0, 0, 0);
            acc[2][1][f] = __builtin_amdgcn_mfma_f32_16x16x32_bf16(au1, bin, acc[2][1][f], 0, 0, 0);

            acc[3][0][f] = __builtin_amdgcn_mfma_f32_16x16x32_bf16(ah0, bhn, acc[3][0][f], 0, 0, 0);
            acc[3][1][f] = __builtin_amdgcn_mfma_f32_16x16x32_bf16(ah1, bhn, acc[3][1][f], 0, 0, 0);
        }
    }

    // ---- epilogue: gates in f32, hprev read f32 ----
    #pragma unroll
    for (int f = 0; f < 2; ++f) {
        int c = cb * 64 + CB0 + f * 16 + li;
        float br = b_ih[c] + b_hh[c];
        float bz = b_ih[c + 512] + b_hh[c + 512];
        float bin_ = b_ih[c + 1024];
        float bhn_ = b_hh[c + 1024];
        #pragma unroll
        for (int fe = 0; fe < 2; ++fe) {
            #pragma unroll
            for (int q = 0; q < 4; ++q) {
                size_t ge = (size_t)(e0 + EB + fe * 16 + (lane >> 4) * 4 + q);
                float r = 1.f / (1.f + __expf(-(acc[0][fe][f][q] + br)));
                float z = 1.f / (1.f + __expf(-(acc[1][fe][f][q] + bz)));
                float n = tanhf(acc[2][fe][f][q] + bin_ + r * (acc[3][fe][f][q] + bhn_));
                float hp = cur[ge * 512 + c];
                nxt[ge * 512 + c] = (1.f - z) * n + z * hp;
            }
        }
    }
}

// MLP + residual, in-place per (e,h) row. one wave per row.
__global__ __launch_bounds__(256) void mlp(float* __restrict__ slots,
                                           const float* __restrict__ lnw,
                                           const float* __restrict__ lnb,
                                           const float* __restrict__ fc1T,
                                           const float* __restrict__ fc1b,
                                           const float* __restrict__ fc2T,
                                           const float* __restrict__ fc2b) {
    __shared__ float sLn[4][64];
    __shared__ float sY1[4][256];
    int lane = threadIdx.x & 63, w = threadIdx.x >> 6;
    size_t row = (size_t)blockIdx.x * 4 + w;     // grid = E*H/4 exactly
    float* base = slots + row * 64;
    float x = base[lane];
    float m = wave_sum(x) * (1.f / 64.f);
    float d = x - m;
    float var = wave_sum(d * d) * (1.f / 64.f);
    float ln = d * rsqrtf(var + 1e-5f) * lnw[lane] + lnb[lane];
    sLn[w][lane] = ln;
    __syncthreads();
    float y[4];
    #pragma unroll
    for (int j = 0; j < 4; ++j) y[j] = fc1b[lane + 64 * j];
    #pragma unroll 4
    for (int dd = 0; dd < 64; ++dd) {
        float vv = sLn[w][dd];
        const float* r = fc1T + dd * 256;
        #pragma unroll
        for (int j = 0; j < 4; ++j) y[j] += vv * r[lane + 64 * j];
    }
    #pragma unroll
    for (int j = 0; j < 4; ++j) sY1[w][lane + 64 * j] = fmaxf(y[j], 0.f);
    __syncthreads();
    float a2 = fc2b[lane];
    #pragma unroll 4
    for (int c = 0; c < 256; ++c) a2 += sY1[w][c] * fc2T[c * 64 + lane];
    base[lane] = x + a2;
}

extern "C" void kernel_launch(void* const* d_in, const int* in_sizes, int n_in,
                              void* d_out, int out_size, void* d_ws, size_t ws_size,
                              hipStream_t stream) {
    const float* x     = (const float*)d_in[0];
    const int*   eidx  = (const int*)d_in[1];
    const float* nd    = (const float*)d_in[3];
    const float* mu    = (const float*)d_in[4];
    const float* lsig  = (const float*)d_in[5];
    const float* atten = (const float*)d_in[6];
    const float* ln_sw = (const float*)d_in[7];
    const float* ln_sb = (const float*)d_in[8];
    const float* ln_mw = (const float*)d_in[9];
    const float* ln_mb = (const float*)d_in[10];
    const float* Wq    = (const float*)d_in[11];
    const float* Wk    = (const float*)d_in[12];
    const float* w_ih  = (const float*)d_in[13];
    const float* w_hh  = (const float*)d_in[14];
    const float* b_ih  = (const float*)d_in[15];
    const float* b_hh  = (const float*)d_in[16];
    const float* fc1w  = (const float*)d_in[17];
    const float* fc1b  = (const float*)d_in[18];
    const float* fc2w  = (const float*)d_in[19];
    const float* fc2b  = (const float*)d_in[20];

    float* out = (float*)d_out;
    char* ws = (char*)d_ws;
    size_t off = 0;
    auto alloc = [&](size_t nbytes) {
        void* p = ws + off;
        off += (nbytes + 255) & ~(size_t)255;
        return p;
    };
    float*          slotsA = (float*)alloc((size_t)E * HD * 4);
    float*          kbuf   = (float*)alloc((size_t)E * 64 * 4);
    float*          alpha  = (float*)alloc((size_t)E * 8 * 4);
    unsigned*       segmax = (unsigned*)alloc((size_t)Nn * 8 * 4);
    float*          segsum = (float*)alloc((size_t)Nn * 8 * 4);
    float*          vbuf   = (float*)alloc(512 * 4);
    float*          fc1T   = (float*)alloc(16384 * 4);
    float*          fc2T   = (float*)alloc(16384 * 4);
    unsigned short* wb     = (unsigned short*)alloc((size_t)3145728 * 2);

    prep_v<<<1, 512, 0, stream>>>(atten, Wq, vbuf);
    prep_fcT<<<128, 256, 0, stream>>>(fc1w, fc2w, fc1T, fc2T);
    wprep<<<12288, 256, 0, stream>>>(w_ih, w_hh, wb);
    compute_k<<<4096, 256, 0, stream>>>(x, Wk, kbuf);
    init_slots<<<2048, 256, 0, stream>>>(nd, mu, lsig, slotsA);

    float* cur = slotsA;
    float* nxt = out;
    for (int it = 0; it < 3; ++it) {
        seg_init<<<512, 256, 0, stream>>>(segmax, segsum);
        alpha_ln<<<E * 8 / 4, 256, 0, stream>>>(cur, vbuf, ln_sw, ln_sb, eidx, alpha, segmax);
        exp_sum<<<E * 8 / 256, 256, 0, stream>>>(eidx, segmax, alpha, segsum);
        norm_alpha<<<E * 8 / 256, 256, 0, stream>>>(eidx, segsum, alpha);
        gru_mfma<<<32768, 256, 0, stream>>>(cur, kbuf, alpha, wb, b_ih, b_hh, nxt);
        mlp<<<E * 8 / 4, 256, 0, stream>>>(nxt, ln_mw, ln_mb, fc1T, fc1b, fc2T, fc2b);
        float* tmp = cur; cur = nxt; nxt = tmp;
    }
    (void)in_sizes; (void)n_in; (void)out_size; (void)ws_size;
}

// Round 3
// 8784.835 us; speedup vs baseline: 50.9757x; 3.5010x over previous
//
#include <hip/hip_runtime.h>
#include <math.h>

#define E 262144
#define Nn 16384
#define H 8
#define D 64
#define HD 512
#define HID 256

typedef float f32x4 __attribute__((ext_vector_type(4)));
typedef short bf16x8 __attribute__((ext_vector_type(8)));

__device__ __forceinline__ float wave_sum(float v) {
    #pragma unroll
    for (int m = 1; m < 64; m <<= 1) v += __shfl_xor(v, m, 64);
    return v;
}

__device__ __forceinline__ unsigned short f2bf(float f) {
    unsigned u = __float_as_uint(f);
    return (unsigned short)((u + 0x7fffu + ((u >> 16) & 1u)) >> 16);
}

// v[h][j] = sum_d atten[h][d] * Wq[d][j]
__global__ void prep_v(const float* __restrict__ atten, const float* __restrict__ Wq,
                       float* __restrict__ v) {
    int t = threadIdx.x;            // 512 threads
    int h = t >> 6, j = t & 63;
    float a = 0.f;
    #pragma unroll 8
    for (int d = 0; d < 64; ++d) a += atten[h * 64 + d] * Wq[d * 64 + j];
    v[h * 64 + j] = a;
}

// MLP weight images (bf16, MFMA-frag layout, kg-XOR bank swizzle baked in):
// B1img[kt(2)][kg(4)][cs(256)][j(8)] = fc1_w[(cs^kg)][kt*32+kg*8+j]
// B2img[kt(8)][kg(4)][ds(64)][j(8)]  = fc2_w[(ds^kg)][kt*32+kg*8+j]
__global__ void prep_mlp(const float* __restrict__ fc1w, const float* __restrict__ fc2w,
                         unsigned short* __restrict__ B1img, unsigned short* __restrict__ B2img) {
    int i = blockIdx.x * 256 + threadIdx.x;   // 32768 total
    if (i < 16384) {
        int j = i & 7, g = i >> 3;
        int cs = g & 255, kgkt = g >> 8;
        int kg = kgkt & 3, kt = kgkt >> 2;
        int c = cs ^ kg;
        int k = kt * 32 + kg * 8 + j;
        B1img[i] = f2bf(fc1w[c * 64 + k]);
    } else {
        int i2 = i - 16384;
        int j = i2 & 7, g = i2 >> 3;
        int ds = g & 63, kgkt = g >> 6;
        int kg = kgkt & 3, kt = kgkt >> 2;
        int dd = ds ^ kg;
        int c = kt * 32 + kg * 8 + j;
        B2img[i2] = f2bf(fc2w[dd * 256 + c]);
    }
}

// GRU weights, bf16, per-kstep LDS image, kg-XOR swizzle baked (cs^kg):
// wb[cb][t][m][kg][cs][j] = w[(m%3)*512 + cb*64 + (cs^kg)][t*32+kg*8+j]
__global__ void wprep(const float* __restrict__ w_ih, const float* __restrict__ w_hh,
                      unsigned short* __restrict__ wb) {
    int o = blockIdx.x * 256 + threadIdx.x;   // 3,145,728 total
    int blk = o / 12288;
    int w = o - blk * 12288;
    int j = w & 7, cs = (w >> 3) & 63, mk = w >> 9;
    int kg = mk & 3, m = mk >> 2;
    int t = blk & 15, cb = blk >> 4;
    const float* wm = (m < 3) ? w_ih : w_hh;
    int row = (m % 3) * 512 + cb * 64 + (cs ^ kg);
    int k = t * 32 + kg * 8 + j;
    wb[o] = f2bf(wm[(size_t)row * 512 + k]);
}

// k[e][d] = 0.125 * sum_j x[e][j] * Wk[d][j]
__global__ __launch_bounds__(256) void compute_k(const float* __restrict__ x,
                                                 const float* __restrict__ Wk,
                                                 float* __restrict__ kbuf) {
    __shared__ float sWk[64][130];
    int t = threadIdx.x;
    for (int i = t; i < 64 * 128; i += 256) sWk[i >> 7][i & 127] = Wk[i];
    __syncthreads();
    int lane = t & 63, w = t >> 6;
    for (int e = blockIdx.x * 4 + w; e < E; e += gridDim.x * 4) {
        const float* xr = x + (size_t)e * 128;
        float acc = 0.f;
        #pragma unroll 8
        for (int j = 0; j < 128; ++j) acc += xr[j] * sWk[lane][j];
        kbuf[(size_t)e * 64 + lane] = acc * 0.125f;
    }
}

// slots = mu + exp(log_sigma) * norm_dist
__global__ void init_slots(const float* __restrict__ nd, const float* __restrict__ mu,
                           const float* __restrict__ lsig, float* __restrict__ out) {
    __shared__ float sMu[64], sSig[64];
    if (threadIdx.x < 64) {
        sMu[threadIdx.x]  = mu[threadIdx.x];
        sSig[threadIdx.x] = __expf(lsig[threadIdx.x]);
    }
    __syncthreads();
    size_t n4 = (size_t)E * HD / 4;
    size_t stride = (size_t)gridDim.x * blockDim.x;
    for (size_t i = (size_t)blockIdx.x * blockDim.x + threadIdx.x; i < n4; i += stride) {
        float4 v = ((const float4*)nd)[i];
        int d0 = (int)((i * 4) & 63);
        v.x = sMu[d0]     + sSig[d0]     * v.x;
        v.y = sMu[d0 + 1] + sSig[d0 + 1] * v.y;
        v.z = sMu[d0 + 2] + sSig[d0 + 2] * v.z;
        v.w = sMu[d0 + 3] + sSig[d0 + 3] * v.w;
        ((float4*)out)[i] = v;
    }
}

__global__ void seg_init(unsigned* __restrict__ segmax, float* __restrict__ segsum) {
    int i = blockIdx.x * 256 + threadIdx.x;
    if (i < Nn * H) { segmax[i] = 0u; segsum[i] = 0.f; }
}

// one wave per (e,h): LN(slots row) -> dot v_h -> leaky_relu -> alpha ; atomicMax into segmax
__global__ __launch_bounds__(256) void alpha_ln(const float* __restrict__ cur,
                                                const float* __restrict__ v,
                                                const float* __restrict__ lnw,
                                                const float* __restrict__ lnb,
                                                const int* __restrict__ eidx,
                                                float* __restrict__ alpha,
                                                unsigned* __restrict__ segmax) {
    int lane = threadIdx.x & 63, w = threadIdx.x >> 6;
    size_t p = (size_t)blockIdx.x * 4 + w;          // grid = E*H/4 exactly
    float x = cur[p * 64 + lane];
    float m = wave_sum(x) * (1.f / 64.f);
    float d = x - m;
    float var = wave_sum(d * d) * (1.f / 64.f);
    float rs = rsqrtf(var + 1e-5f);
    float ln = d * rs * lnw[lane] + lnb[lane];
    int h = (int)(p & 7);
    float dot = wave_sum(ln * v[h * 64 + lane]) * 0.125f;
    float a = dot >= 0.f ? dot : 0.2f * dot;
    if (lane == 0) {
        alpha[p] = a;
        int e = (int)(p >> 3);
        int id = eidx[e];
        unsigned b = __float_as_uint(a);
        unsigned enc = (b & 0x80000000u) ? ~b : (b | 0x80000000u);
        atomicMax(&segmax[id * 8 + h], enc);
    }
}

__global__ void exp_sum(const int* __restrict__ eidx, const unsigned* __restrict__ segmax,
                        float* __restrict__ alpha, float* __restrict__ segsum) {
    size_t p = (size_t)blockIdx.x * 256 + threadIdx.x;
    int e = (int)(p >> 3), h = (int)(p & 7);
    int id = eidx[e];
    unsigned u = segmax[id * 8 + h];
    float m = __uint_as_float((u & 0x80000000u) ? (u & 0x7fffffffu) : ~u);
    float val = __expf(alpha[p] - m);
    alpha[p] = val;
    atomicAdd(&segsum[id * 8 + h], val);
}

__global__ void norm_alpha(const int* __restrict__ eidx, const float* __restrict__ segsum,
                           float* __restrict__ alpha) {
    size_t p = (size_t)blockIdx.x * 256 + threadIdx.x;
    int e = (int)(p >> 3), h = (int)(p & 7);
    alpha[p] = alpha[p] / (segsum[eidx[e] * 8 + h] + 1e-16f);
}

// ---------------- MFMA GRU ----------------
__global__ __launch_bounds__(256, 2) void gru_mfma(
    const float* __restrict__ cur, const float* __restrict__ kbuf,
    const float* __restrict__ alpha, const unsigned short* __restrict__ wb,
    const float* __restrict__ b_ih, const float* __restrict__ b_hh,
    float* __restrict__ nxt) {

    __shared__ unsigned short Au[2048];   // [kg][e 0..63][8]  (XOR-swizzled)
    __shared__ unsigned short Ah[2048];
    __shared__ unsigned short Bl[12288];  // [m 0..5][kg][cs 0..63][8] = wb image (cs = c^kg)

    int bid = blockIdx.x;
    int lbid = (bid & 7) * 4096 + (bid >> 3);   // XCD-contiguous chunks
    int eb = lbid >> 3, cb = lbid & 7;
    int e0 = eb * 64;

    int t = threadIdx.x;
    int lane = t & 63, wid = t >> 6;
    int wr = wid >> 1, wc = wid & 1;
    int EB = wr * 32, CB0 = wc * 32;
    int kg = lane >> 4, li = lane & 15;

    int se = t & 63, skg = t >> 6;   // staging role: edge, k-group

    f32x4 acc[4][2][2] = {};   // [plane][fe][f]

    for (int k0 = 0; k0 < 512; k0 += 32) {
        __syncthreads();
        // ---- stage A (updates = kbuf*alpha, hprev = cur), f32 -> bf16 ----
        {
            size_t ge = (size_t)(e0 + se);
            float al = alpha[ge * 8 + (k0 >> 6)];
            const float* kb = kbuf + ge * 64 + (k0 & 63) + skg * 8;
            const float* hb = cur + ge * 512 + k0 + skg * 8;
            float4 ku0 = *(const float4*)kb, ku1 = *(const float4*)(kb + 4);
            float4 hh0 = *(const float4*)hb, hh1 = *(const float4*)(hb + 4);
            bf16x8 uv, hv;
            uv[0] = (short)f2bf(ku0.x * al); uv[1] = (short)f2bf(ku0.y * al);
            uv[2] = (short)f2bf(ku0.z * al); uv[3] = (short)f2bf(ku0.w * al);
            uv[4] = (short)f2bf(ku1.x * al); uv[5] = (short)f2bf(ku1.y * al);
            uv[6] = (short)f2bf(ku1.z * al); uv[7] = (short)f2bf(ku1.w * al);
            hv[0] = (short)f2bf(hh0.x); hv[1] = (short)f2bf(hh0.y);
            hv[2] = (short)f2bf(hh0.z); hv[3] = (short)f2bf(hh0.w);
            hv[4] = (short)f2bf(hh1.x); hv[5] = (short)f2bf(hh1.y);
            hv[6] = (short)f2bf(hh1.z); hv[7] = (short)f2bf(hh1.w);
            int ao = skg * 512 + ((se * 8) ^ (skg * 8));
            *(bf16x8*)(Au + ao) = uv;
            *(bf16x8*)(Ah + ao) = hv;
        }
        // ---- stage B: linear 24KB copy of pre-swizzled weights ----
        {
            const float4* src = (const float4*)(wb + (size_t)(cb * 16 + (k0 >> 5)) * 12288);
            float4* dst = (float4*)Bl;
            #pragma unroll
            for (int q = 0; q < 6; ++q) dst[t + q * 256] = src[t + q * 256];
        }
        __syncthreads();

        // ---- fragments ----
        bf16x8 au0 = *(bf16x8*)(Au + kg * 512 + (((EB + li) * 8) ^ (kg * 8)));
        bf16x8 au1 = *(bf16x8*)(Au + kg * 512 + (((EB + 16 + li) * 8) ^ (kg * 8)));
        bf16x8 ah0 = *(bf16x8*)(Ah + kg * 512 + (((EB + li) * 8) ^ (kg * 8)));
        bf16x8 ah1 = *(bf16x8*)(Ah + kg * 512 + (((EB + 16 + li) * 8) ^ (kg * 8)));

        #pragma unroll
        for (int f = 0; f < 2; ++f) {
            int c8 = ((CB0 + f * 16 + li) ^ kg) * 8;   // kg-XOR de-swizzle
            bf16x8 bir = *(bf16x8*)(Bl + (0 * 4 + kg) * 512 + c8);
            bf16x8 biz = *(bf16x8*)(Bl + (1 * 4 + kg) * 512 + c8);
            bf16x8 bin = *(bf16x8*)(Bl + (2 * 4 + kg) * 512 + c8);
            bf16x8 bhr = *(bf16x8*)(Bl + (3 * 4 + kg) * 512 + c8);
            bf16x8 bhz = *(bf16x8*)(Bl + (4 * 4 + kg) * 512 + c8);
            bf16x8 bhn = *(bf16x8*)(Bl + (5 * 4 + kg) * 512 + c8);

            acc[0][0][f] = __builtin_amdgcn_mfma_f32_16x16x32_bf16(au0, bir, acc[0][0][f], 0, 0, 0);
            acc[0][0][f] = __builtin_amdgcn_mfma_f32_16x16x32_bf16(ah0, bhr, acc[0][0][f], 0, 0, 0);
            acc[0][1][f] = __builtin_amdgcn_mfma_f32_16x16x32_bf16(au1, bir, acc[0][1][f], 0, 0, 0);
            acc[0][1][f] = __builtin_amdgcn_mfma_f32_16x16x32_bf16(ah1, bhr, acc[0][1][f], 0, 0, 0);

            acc[1][0][f] = __builtin_amdgcn_mfma_f32_16x16x32_bf16(au0, biz, acc[1][0][f], 0, 0, 0);
            acc[1][0][f] = __builtin_amdgcn_mfma_f32_16x16x32_bf16(ah0, bhz, acc[1][0][f], 0, 0, 0);
            acc[1][1][f] = __builtin_amdgcn_mfma_f32_16x16x32_bf16(au1, biz, acc[1][1][f], 0, 0, 0);
            acc[1][1][f] = __builtin_amdgcn_mfma_f32_16x16x32_bf16(ah1, bhz, acc[1][1][f], 0, 0, 0);

            acc[2][0][f] = __builtin_amdgcn_mfma_f32_16x16x32_bf16(au0, bin, acc[2][0][f], 0, 0, 0);
            acc[2][1][f] = __builtin_amdgcn_mfma_f32_16x16x32_bf16(au1, bin, acc[2][1][f], 0, 0, 0);

            acc[3][0][f] = __builtin_amdgcn_mfma_f32_16x16x32_bf16(ah0, bhn, acc[3][0][f], 0, 0, 0);
            acc[3][1][f] = __builtin_amdgcn_mfma_f32_16x16x32_bf16(ah1, bhn, acc[3][1][f], 0, 0, 0);
        }
    }

    // ---- epilogue: gates in f32, hprev read f32 ----
    #pragma unroll
    for (int f = 0; f < 2; ++f) {
        int c = cb * 64 + CB0 + f * 16 + li;
        float br = b_ih[c] + b_hh[c];
        float bz = b_ih[c + 512] + b_hh[c + 512];
        float bin_ = b_ih[c + 1024];
        float bhn_ = b_hh[c + 1024];
        #pragma unroll
        for (int fe = 0; fe < 2; ++fe) {
            #pragma unroll
            for (int q = 0; q < 4; ++q) {
                size_t ge = (size_t)(e0 + EB + fe * 16 + (lane >> 4) * 4 + q);
                float r = 1.f / (1.f + __expf(-(acc[0][fe][f][q] + br)));
                float z = 1.f / (1.f + __expf(-(acc[1][fe][f][q] + bz)));
                float n = tanhf(acc[2][fe][f][q] + bin_ + r * (acc[3][fe][f][q] + bhn_));
                float hp = cur[ge * 512 + c];
                nxt[ge * 512 + c] = (1.f - z) * n + z * hp;
            }
        }
    }
}

// ---------------- MFMA MLP (fused LN + fc1 + relu + fc2 + residual) ----------------
// Block: 64 rows (row = (e,h) flat). fc1 operand-swapped so lane holds 4
// consecutive hidden-cols -> b64 packed Y1 writes. In-place on slots.
__global__ __launch_bounds__(256, 2) void mlp_mfma(
    float* __restrict__ slots,
    const unsigned short* __restrict__ B1img, const unsigned short* __restrict__ B2img,
    const float* __restrict__ lnw, const float* __restrict__ lnb,
    const float* __restrict__ fc1b, const float* __restrict__ fc2b) {

    __shared__ unsigned short A1[4096];    // [g(8)][row(64)][j(8)], row^kg swz : 8 KB
    __shared__ unsigned short Bst[8192];   // weight staging chunk              : 16 KB
    __shared__ unsigned short Y1[16384];   // [g(32)][row(64)][j(8)], row^kg swz: 32 KB

    int t = threadIdx.x;
    int lane = t & 63, wid = t >> 6;
    int li = lane & 15, kg = lane >> 4;
    size_t p0 = (size_t)blockIdx.x * 64;

    // ---- phase 0: load rows, LN (4 threads/row), bf16 A1 tile ----
    {
        int r = t >> 2, c0 = (t & 3) * 16;
        const float* rowp = slots + (p0 + r) * 64 + c0;
        float4 x0 = ((const float4*)rowp)[0];
        float4 x1 = ((const float4*)rowp)[1];
        float4 x2 = ((const float4*)rowp)[2];
        float4 x3 = ((const float4*)rowp)[3];
        float s = x0.x + x0.y + x0.z + x0.w + x1.x + x1.y + x1.z + x1.w
                + x2.x + x2.y + x2.z + x2.w + x3.x + x3.y + x3.z + x3.w;
        s += __shfl_xor(s, 1, 64); s += __shfl_xor(s, 2, 64);
        float m = s * (1.f / 64.f);
        float xv[16] = {x0.x, x0.y, x0.z, x0.w, x1.x, x1.y, x1.z, x1.w,
                        x2.x, x2.y, x2.z, x2.w, x3.x, x3.y, x3.z, x3.w};
        float sq = 0.f;
        #pragma unroll
        for (int i = 0; i < 16; ++i) { float dd = xv[i] - m; sq += dd * dd; }
        sq += __shfl_xor(sq, 1, 64); sq += __shfl_xor(sq, 2, 64);
        float rs = rsqrtf(sq * (1.f / 64.f) + 1e-5f);
        unsigned short u[16];
        #pragma unroll
        for (int i = 0; i < 16; ++i)
            u[i] = f2bf((xv[i] - m) * rs * lnw[c0 + i] + lnb[c0 + i]);
        int g0 = (t & 3) * 2, g1 = g0 + 1;
        *(bf16x8*)(A1 + g0 * 512 + ((r * 8) ^ ((g0 & 3) * 8))) = *(bf16x8*)&u[0];
        *(bf16x8*)(A1 + g1 * 512 + ((r * 8) ^ ((g1 & 3) * 8))) = *(bf16x8*)&u[8];
    }
    __syncthreads();

    // ---- fc1 (swapped): acc1[ct][rt], lane = (row li, 4 consecutive c) ----
    f32x4 acc1[4][4] = {};
    #pragma unroll
    for (int kt = 0; kt < 2; ++kt) {
        {   // stage 16KB chunk of B1img
            const float4* src = (const float4*)(B1img + kt * 8192);
            float4* dst = (float4*)Bst;
            #pragma unroll
            for (int q = 0; q < 4; ++q) dst[t + q * 256] = src[t + q * 256];
        }
        __syncthreads();
        bf16x8 bfrag[4];
        #pragma unroll
        for (int rt = 0; rt < 4; ++rt)
            bfrag[rt] = *(bf16x8*)(A1 + (kt * 4 + kg) * 512 + (((rt * 16 + li) * 8) ^ (kg * 8)));
        #pragma unroll
        for (int ct = 0; ct < 4; ++ct) {
            bf16x8 af = *(bf16x8*)(Bst + kg * 2048 + (((wid * 64 + ct * 16 + li) ^ kg) * 8));
            #pragma unroll
            for (int rt = 0; rt < 4; ++rt)
                acc1[ct][rt] = __builtin_amdgcn_mfma_f32_16x16x32_bf16(af, bfrag[rt], acc1[ct][rt], 0, 0, 0);
        }
        __syncthreads();
    }

    // ---- bias + relu + bf16, packed b64 writes into Y1 ----
    #pragma unroll
    for (int ct = 0; ct < 4; ++ct) {
        int c0 = wid * 64 + ct * 16 + kg * 4;
        float4 b1 = *(const float4*)(fc1b + c0);
        int g = c0 >> 3;
        #pragma unroll
        for (int rt = 0; rt < 4; ++rt) {
            f32x4 vv = acc1[ct][rt];
            float y0 = fmaxf(vv[0] + b1.x, 0.f), y1v = fmaxf(vv[1] + b1.y, 0.f);
            float y2 = fmaxf(vv[2] + b1.z, 0.f), y3 = fmaxf(vv[3] + b1.w, 0.f);
            unsigned lo = (unsigned)f2bf(y0) | ((unsigned)f2bf(y1v) << 16);
            unsigned hi = (unsigned)f2bf(y2) | ((unsigned)f2bf(y3) << 16);
            int r = rt * 16 + li;
            int off = g * 512 + ((r * 8) ^ ((g & 3) * 8)) + (c0 & 7);
            uint2 pk; pk.x = lo; pk.y = hi;
            *(uint2*)(Y1 + off) = pk;
        }
    }
    __syncthreads();

    // ---- fc2: wave wid owns rows wid*16..+15; K=256 in 2 staged chunks ----
    f32x4 acc2[4] = {};
    #pragma unroll
    for (int hc = 0; hc < 2; ++hc) {
        {   // stage 16KB chunk of B2img
            const float4* src = (const float4*)(B2img + hc * 8192);
            float4* dst = (float4*)Bst;
            #pragma unroll
            for (int q = 0; q < 4; ++q) dst[t + q * 256] = src[t + q * 256];
        }
        __syncthreads();
        #pragma unroll
        for (int ktl = 0; ktl < 4; ++ktl) {
            int ktg = hc * 4 + ktl;
            bf16x8 af = *(bf16x8*)(Y1 + (ktg * 4 + kg) * 512 + (((wid * 16 + li) * 8) ^ (kg * 8)));
            #pragma unroll
            for (int nt = 0; nt < 4; ++nt) {
                bf16x8 bf = *(bf16x8*)(Bst + (ktl * 4 + kg) * 512 + (((nt * 16 + li) ^ kg) * 8));
                acc2[nt] = __builtin_amdgcn_mfma_f32_16x16x32_bf16(af, bf, acc2[nt], 0, 0, 0);
            }
        }
        __syncthreads();
    }

    // ---- epilogue: residual add, in-place ----
    #pragma unroll
    for (int nt = 0; nt < 4; ++nt) {
        int dd = nt * 16 + li;
        float b2 = fc2b[dd];
        #pragma unroll
        for (int q = 0; q < 4; ++q) {
            int r = wid * 16 + kg * 4 + q;
            size_t gp = (p0 + r) * 64 + dd;
            slots[gp] = slots[gp] + acc2[nt][q] + b2;
        }
    }
}

extern "C" void kernel_launch(void* const* d_in, const int* in_sizes, int n_in,
                              void* d_out, int out_size, void* d_ws, size_t ws_size,
                              hipStream_t stream) {
    const float* x     = (const float*)d_in[0];
    const int*   eidx  = (const int*)d_in[1];
    const float* nd    = (const float*)d_in[3];
    const float* mu    = (const float*)d_in[4];
    const float* lsig  = (const float*)d_in[5];
    const float* atten = (const float*)d_in[6];
    const float* ln_sw = (const float*)d_in[7];
    const float* ln_sb = (const float*)d_in[8];
    const float* ln_mw = (const float*)d_in[9];
    const float* ln_mb = (const float*)d_in[10];
    const float* Wq    = (const float*)d_in[11];
    const float* Wk    = (const float*)d_in[12];
    const float* w_ih  = (const float*)d_in[13];
    const float* w_hh  = (const float*)d_in[14];
    const float* b_ih  = (const float*)d_in[15];
    const float* b_hh  = (const float*)d_in[16];
    const float* fc1w  = (const float*)d_in[17];
    const float* fc1b  = (const float*)d_in[18];
    const float* fc2w  = (const float*)d_in[19];
    const float* fc2b  = (const float*)d_in[20];

    float* out = (float*)d_out;
    char* ws = (char*)d_ws;
    size_t off = 0;
    auto alloc = [&](size_t nbytes) {
        void* p = ws + off;
        off += (nbytes + 255) & ~(size_t)255;
        return p;
    };
    float*          slotsA = (float*)alloc((size_t)E * HD * 4);
    float*          kbuf   = (float*)alloc((size_t)E * 64 * 4);
    float*          alpha  = (float*)alloc((size_t)E * 8 * 4);
    unsigned*       segmax = (unsigned*)alloc((size_t)Nn * 8 * 4);
    float*          segsum = (float*)alloc((size_t)Nn * 8 * 4);
    float*          vbuf   = (float*)alloc(512 * 4);
    unsigned short* B1img  = (unsigned short*)alloc(16384 * 2);
    unsigned short* B2img  = (unsigned short*)alloc(16384 * 2);
    unsigned short* wb     = (unsigned short*)alloc((size_t)3145728 * 2);

    prep_v<<<1, 512, 0, stream>>>(atten, Wq, vbuf);
    prep_mlp<<<128, 256, 0, stream>>>(fc1w, fc2w, B1img, B2img);
    wprep<<<12288, 256, 0, stream>>>(w_ih, w_hh, wb);
    compute_k<<<4096, 256, 0, stream>>>(x, Wk, kbuf);
    init_slots<<<2048, 256, 0, stream>>>(nd, mu, lsig, slotsA);

    float* cur = slotsA;
    float* nxt = out;
    for (int it = 0; it < 3; ++it) {
        seg_init<<<512, 256, 0, stream>>>(segmax, segsum);
        alpha_ln<<<E * 8 / 4, 256, 0, stream>>>(cur, vbuf, ln_sw, ln_sb, eidx, alpha, segmax);
        exp_sum<<<E * 8 / 256, 256, 0, stream>>>(eidx, segmax, alpha, segsum);
        norm_alpha<<<E * 8 / 256, 256, 0, stream>>>(eidx, segsum, alpha);
        gru_mfma<<<32768, 256, 0, stream>>>(cur, kbuf, alpha, wb, b_ih, b_hh, nxt);
        mlp_mfma<<<32768, 256, 0, stream>>>(nxt, B1img, B2img, ln_mw, ln_mb, fc1b, fc2b);
        float* tmp = cur; cur = nxt; nxt = tmp;
    }
    (void)in_sizes; (void)n_in; (void)out_size; (void)ws_size;
}

// Round 4
// 8445.535 us; speedup vs baseline: 53.0237x; 1.0402x over previous
//
#include <hip/hip_runtime.h>
#include <math.h>

#define E 262144
#define Nn 16384
#define H 8
#define D 64
#define HD 512
#define HID 256

typedef float f32x4 __attribute__((ext_vector_type(4)));
typedef short bf16x8 __attribute__((ext_vector_type(8)));

__device__ __forceinline__ float wave_sum(float v) {
    #pragma unroll
    for (int m = 1; m < 64; m <<= 1) v += __shfl_xor(v, m, 64);
    return v;
}

__device__ __forceinline__ unsigned short f2bf(float f) {
    unsigned u = __float_as_uint(f);
    return (unsigned short)((u + 0x7fffu + ((u >> 16) & 1u)) >> 16);
}

__device__ __forceinline__ void gl_lds16(const void* g, void* l) {
    __builtin_amdgcn_global_load_lds(
        (const __attribute__((address_space(1))) void*)g,
        (__attribute__((address_space(3))) void*)l, 16, 0, 0);
}

// v[h][j] = sum_d atten[h][d] * Wq[d][j]
__global__ void prep_v(const float* __restrict__ atten, const float* __restrict__ Wq,
                       float* __restrict__ v) {
    int t = threadIdx.x;            // 512 threads
    int h = t >> 6, j = t & 63;
    float a = 0.f;
    #pragma unroll 8
    for (int d = 0; d < 64; ++d) a += atten[h * 64 + d] * Wq[d * 64 + j];
    v[h * 64 + j] = a;
}

// MLP weight images (bf16, MFMA-frag layout, kg-XOR bank swizzle baked in)
__global__ void prep_mlp(const float* __restrict__ fc1w, const float* __restrict__ fc2w,
                         unsigned short* __restrict__ B1img, unsigned short* __restrict__ B2img) {
    int i = blockIdx.x * 256 + threadIdx.x;   // 32768 total
    if (i < 16384) {
        int j = i & 7, g = i >> 3;
        int cs = g & 255, kgkt = g >> 8;
        int kg = kgkt & 3, kt = kgkt >> 2;
        int c = cs ^ kg;
        int k = kt * 32 + kg * 8 + j;
        B1img[i] = f2bf(fc1w[c * 64 + k]);
    } else {
        int i2 = i - 16384;
        int j = i2 & 7, g = i2 >> 3;
        int ds = g & 63, kgkt = g >> 6;
        int kg = kgkt & 3, kt = kgkt >> 2;
        int dd = ds ^ kg;
        int c = kt * 32 + kg * 8 + j;
        B2img[i2] = f2bf(fc2w[dd * 256 + c]);
    }
}

// GRU weights bf16 image for BN=32:
// wb[cb(16)][t(16)][m(6)][kg(4)][cs(32)][j(8)] = w[(m%3)*512 + cb*32 + (cs^kg)][t*32+kg*8+j]
__global__ void wprep(const float* __restrict__ w_ih, const float* __restrict__ w_hh,
                      unsigned short* __restrict__ wb) {
    int o = blockIdx.x * 256 + threadIdx.x;   // 1,572,864 total
    int slice = o / 6144;
    int w = o - slice * 6144;
    int t = slice & 15, cb = slice >> 4;
    int j = w & 7;
    int cs = (w >> 3) & 31;
    int kgm = w >> 8;
    int kg = kgm & 3, m = kgm >> 2;
    const float* wm = (m < 3) ? w_ih : w_hh;
    int row = (m % 3) * 512 + cb * 32 + (cs ^ kg);
    int k = t * 32 + kg * 8 + j;
    wb[o] = f2bf(wm[(size_t)row * 512 + k]);
}

// k[e][d] = 0.125 * sum_j x[e][j] * Wk[d][j]
__global__ __launch_bounds__(256) void compute_k(const float* __restrict__ x,
                                                 const float* __restrict__ Wk,
                                                 float* __restrict__ kbuf) {
    __shared__ float sWk[64][130];
    int t = threadIdx.x;
    for (int i = t; i < 64 * 128; i += 256) sWk[i >> 7][i & 127] = Wk[i];
    __syncthreads();
    int lane = t & 63, w = t >> 6;
    for (int e = blockIdx.x * 4 + w; e < E; e += gridDim.x * 4) {
        const float* xr = x + (size_t)e * 128;
        float acc = 0.f;
        #pragma unroll 8
        for (int j = 0; j < 128; ++j) acc += xr[j] * sWk[lane][j];
        kbuf[(size_t)e * 64 + lane] = acc * 0.125f;
    }
}

// slots = mu + exp(log_sigma) * norm_dist ; also emit bf16 h_g image
__global__ void init_slots(const float* __restrict__ nd, const float* __restrict__ mu,
                           const float* __restrict__ lsig, float* __restrict__ out,
                           unsigned short* __restrict__ h_g) {
    __shared__ float sMu[64], sSig[64];
    if (threadIdx.x < 64) {
        sMu[threadIdx.x]  = mu[threadIdx.x];
        sSig[threadIdx.x] = __expf(lsig[threadIdx.x]);
    }
    __syncthreads();
    size_t n4 = (size_t)E * HD / 4;
    size_t stride = (size_t)gridDim.x * blockDim.x;
    for (size_t i = (size_t)blockIdx.x * blockDim.x + threadIdx.x; i < n4; i += stride) {
        float4 v = ((const float4*)nd)[i];
        size_t flat = i * 4;
        int d0 = (int)(flat & 63);
        v.x = sMu[d0]     + sSig[d0]     * v.x;
        v.y = sMu[d0 + 1] + sSig[d0 + 1] * v.y;
        v.z = sMu[d0 + 2] + sSig[d0 + 2] * v.z;
        v.w = sMu[d0 + 3] + sSig[d0 + 3] * v.w;
        ((float4*)out)[i] = v;
        int e = (int)(flat >> 9);
        int k = (int)(flat & 511);
        int tt = k >> 5, kgg = (k >> 3) & 3, jo = k & 7;  // jo in {0,4}
        uint2 pk;
        pk.x = (unsigned)f2bf(v.x) | ((unsigned)f2bf(v.y) << 16);
        pk.y = (unsigned)f2bf(v.z) | ((unsigned)f2bf(v.w) << 16);
        *(uint2*)(h_g + ((size_t)(tt * 4 + kgg) * E + e) * 8 + jo) = pk;
    }
}

__global__ void seg_init(unsigned* __restrict__ segmax, float* __restrict__ segsum) {
    int i = blockIdx.x * 256 + threadIdx.x;
    if (i < Nn * H) { segmax[i] = 0u; segsum[i] = 0.f; }
}

// one wave per (e,h): LN(slots row) -> dot v_h -> leaky_relu -> alpha ; atomicMax into segmax
__global__ __launch_bounds__(256) void alpha_ln(const float* __restrict__ cur,
                                                const float* __restrict__ v,
                                                const float* __restrict__ lnw,
                                                const float* __restrict__ lnb,
                                                const int* __restrict__ eidx,
                                                float* __restrict__ alpha,
                                                unsigned* __restrict__ segmax) {
    int lane = threadIdx.x & 63, w = threadIdx.x >> 6;
    size_t p = (size_t)blockIdx.x * 4 + w;          // grid = E*H/4 exactly
    float x = cur[p * 64 + lane];
    float m = wave_sum(x) * (1.f / 64.f);
    float d = x - m;
    float var = wave_sum(d * d) * (1.f / 64.f);
    float rs = rsqrtf(var + 1e-5f);
    float ln = d * rs * lnw[lane] + lnb[lane];
    int h = (int)(p & 7);
    float dot = wave_sum(ln * v[h * 64 + lane]) * 0.125f;
    float a = dot >= 0.f ? dot : 0.2f * dot;
    if (lane == 0) {
        alpha[p] = a;
        int e = (int)(p >> 3);
        int id = eidx[e];
        unsigned b = __float_as_uint(a);
        unsigned enc = (b & 0x80000000u) ? ~b : (b | 0x80000000u);
        atomicMax(&segmax[id * 8 + h], enc);
    }
}

__global__ void exp_sum(const int* __restrict__ eidx, const unsigned* __restrict__ segmax,
                        float* __restrict__ alpha, float* __restrict__ segsum) {
    size_t p = (size_t)blockIdx.x * 256 + threadIdx.x;
    int e = (int)(p >> 3), h = (int)(p & 7);
    int id = eidx[e];
    unsigned u = segmax[id * 8 + h];
    float m = __uint_as_float((u & 0x80000000u) ? (u & 0x7fffffffu) : ~u);
    float val = __expf(alpha[p] - m);
    alpha[p] = val;
    atomicAdd(&segsum[id * 8 + h], val);
}

// normalize alpha + build u_g = bf16((k*alpha)) in [t][kg][E][8] layout. thread per edge.
__global__ __launch_bounds__(256) void prep_u(const float* __restrict__ kbuf,
                                              const float* __restrict__ alpha,
                                              const float* __restrict__ segsum,
                                              const int* __restrict__ eidx,
                                              unsigned short* __restrict__ u_g) {
    int e = blockIdx.x * 256 + threadIdx.x;
    int id = eidx[e];
    float a[8];
    #pragma unroll
    for (int h = 0; h < 8; ++h)
        a[h] = alpha[(size_t)e * 8 + h] / (segsum[id * 8 + h] + 1e-16f);
    float4 kv[16];
    const float4* kr = (const float4*)(kbuf + (size_t)e * 64);
    #pragma unroll
    for (int q = 0; q < 16; ++q) kv[q] = kr[q];
    const float* kf = (const float*)kv;
    #pragma unroll
    for (int tt = 0; tt < 16; ++tt) {
        float ah = a[tt >> 1];
        #pragma unroll
        for (int kg = 0; kg < 4; ++kg) {
            int dbase = (tt & 1) * 32 + kg * 8;
            bf16x8 v;
            #pragma unroll
            for (int j = 0; j < 8; ++j) v[j] = (short)f2bf(kf[dbase + j] * ah);
            *(bf16x8*)(u_g + ((size_t)(tt * 4 + kg) * E + e) * 8) = v;
        }
    }
}

// ---------------- MFMA GRU : BM=256 edges x BN=32 cols, BK=32, gload_lds ----------------
__global__ __launch_bounds__(256, 2) void gru_mfma(
    const float* __restrict__ cur, const unsigned short* __restrict__ u_g,
    const unsigned short* __restrict__ h_g, const unsigned short* __restrict__ wb,
    const float* __restrict__ b_ih, const float* __restrict__ b_hh,
    float* __restrict__ nxt) {

    // entries (16B each): Au [0,1024) = [kg(4)][el(256)], Ah [1024,2048), W [2048,2816)
    __shared__ unsigned short lds[22528];   // 44 KB

    int bid = blockIdx.x;
    int lbid = (bid & 7) * 2048 + (bid >> 3);   // XCD-contiguous chunks (16384 % 8 == 0)
    int eb = lbid >> 4, cb = lbid & 15;
    int e0 = eb * 256;
    int t = threadIdx.x;
    int lane = t & 63, wid = t >> 6;
    int li = lane & 15, kg = lane >> 4;
    int EB = wid * 64;

    const unsigned short* wsl = wb + (size_t)(cb * 16) * 6144;

    f32x4 acc[4][4][2] = {};   // [plane][m][f]

    for (int ts = 0; ts < 16; ++ts) {
        __syncthreads();                        // everyone done reading LDS
        {   // stage 2816 entries via global_load_lds (11 per thread)
            #pragma unroll
            for (int c = 0; c < 11; ++c) {
                int i = c * 256 + t;
                unsigned short* lp = lds + (size_t)(c * 256 + (t & ~63)) * 8;
                const unsigned short* gp;
                if (c < 4) {
                    int kgg = i >> 8, el = i & 255;
                    gp = u_g + ((size_t)(ts * 4 + kgg) * E + (e0 + el)) * 8;
                } else if (c < 8) {
                    int i2 = i - 1024; int kgg = i2 >> 8, el = i2 & 255;
                    gp = h_g + ((size_t)(ts * 4 + kgg) * E + (e0 + el)) * 8;
                } else {
                    gp = wsl + (size_t)ts * 6144 + (size_t)(i - 2048) * 8;
                }
                gl_lds16(gp, lp);
            }
        }
        __syncthreads();                        // drains vmcnt -> LDS ready

        bf16x8 au[4], ah[4];
        #pragma unroll
        for (int m = 0; m < 4; ++m) {
            int ea = kg * 256 + EB + m * 16 + li;
            au[m] = *(bf16x8*)(lds + ea * 8);
            ah[m] = *(bf16x8*)(lds + (1024 + ea) * 8);
        }
        #pragma unroll
        for (int f = 0; f < 2; ++f) {
            int cs = (f * 16 + li) ^ kg;
            const unsigned short* W = lds + 2048 * 8;
            bf16x8 bir = *(bf16x8*)(W + ((0 * 4 + kg) * 32 + cs) * 8);
            bf16x8 biz = *(bf16x8*)(W + ((1 * 4 + kg) * 32 + cs) * 8);
            bf16x8 bin = *(bf16x8*)(W + ((2 * 4 + kg) * 32 + cs) * 8);
            bf16x8 bhr = *(bf16x8*)(W + ((3 * 4 + kg) * 32 + cs) * 8);
            bf16x8 bhz = *(bf16x8*)(W + ((4 * 4 + kg) * 32 + cs) * 8);
            bf16x8 bhn = *(bf16x8*)(W + ((5 * 4 + kg) * 32 + cs) * 8);
            #pragma unroll
            for (int m = 0; m < 4; ++m) {
                acc[0][m][f] = __builtin_amdgcn_mfma_f32_16x16x32_bf16(au[m], bir, acc[0][m][f], 0, 0, 0);
                acc[0][m][f] = __builtin_amdgcn_mfma_f32_16x16x32_bf16(ah[m], bhr, acc[0][m][f], 0, 0, 0);
                acc[1][m][f] = __builtin_amdgcn_mfma_f32_16x16x32_bf16(au[m], biz, acc[1][m][f], 0, 0, 0);
                acc[1][m][f] = __builtin_amdgcn_mfma_f32_16x16x32_bf16(ah[m], bhz, acc[1][m][f], 0, 0, 0);
                acc[2][m][f] = __builtin_amdgcn_mfma_f32_16x16x32_bf16(au[m], bin, acc[2][m][f], 0, 0, 0);
                acc[3][m][f] = __builtin_amdgcn_mfma_f32_16x16x32_bf16(ah[m], bhn, acc[3][m][f], 0, 0, 0);
            }
        }
    }

    // epilogue: gates f32
    #pragma unroll
    for (int f = 0; f < 2; ++f) {
        int c = cb * 32 + f * 16 + li;
        float br = b_ih[c] + b_hh[c];
        float bz = b_ih[c + 512] + b_hh[c + 512];
        float bi = b_ih[c + 1024];
        float bh = b_hh[c + 1024];
        #pragma unroll
        for (int m = 0; m < 4; ++m) {
            #pragma unroll
            for (int q = 0; q < 4; ++q) {
                size_t ge = (size_t)(e0 + EB + m * 16 + kg * 4 + q);
                float r = 1.f / (1.f + __expf(-(acc[0][m][f][q] + br)));
                float z = 1.f / (1.f + __expf(-(acc[1][m][f][q] + bz)));
                float n = tanhf(acc[2][m][f][q] + bi + r * (acc[3][m][f][q] + bh));
                float hp = cur[ge * 512 + c];
                nxt[ge * 512 + c] = (1.f - z) * n + z * hp;
            }
        }
    }
}

// ---------------- MFMA MLP (fused LN + fc1 + relu + fc2 + residual + h_g emit) ----------------
__global__ __launch_bounds__(256, 2) void mlp_mfma(
    float* __restrict__ slots,
    const unsigned short* __restrict__ B1img, const unsigned short* __restrict__ B2img,
    const float* __restrict__ lnw, const float* __restrict__ lnb,
    const float* __restrict__ fc1b, const float* __restrict__ fc2b,
    unsigned short* __restrict__ h_g, int write_hg) {

    __shared__ unsigned short A1[4096];    // frag tile, later reused as [row64][d64] bf16
    __shared__ unsigned short Bst[8192];   // weight staging chunk 16 KB
    __shared__ unsigned short Y1[16384];   // 32 KB

    int t = threadIdx.x;
    int lane = t & 63, wid = t >> 6;
    int li = lane & 15, kg = lane >> 4;
    size_t p0 = (size_t)blockIdx.x * 64;

    // ---- phase 0: load rows, LN (4 threads/row), bf16 A1 tile ----
    {
        int r = t >> 2, c0 = (t & 3) * 16;
        const float* rowp = slots + (p0 + r) * 64 + c0;
        float4 x0 = ((const float4*)rowp)[0];
        float4 x1 = ((const float4*)rowp)[1];
        float4 x2 = ((const float4*)rowp)[2];
        float4 x3 = ((const float4*)rowp)[3];
        float s = x0.x + x0.y + x0.z + x0.w + x1.x + x1.y + x1.z + x1.w
                + x2.x + x2.y + x2.z + x2.w + x3.x + x3.y + x3.z + x3.w;
        s += __shfl_xor(s, 1, 64); s += __shfl_xor(s, 2, 64);
        float m = s * (1.f / 64.f);
        float xv[16] = {x0.x, x0.y, x0.z, x0.w, x1.x, x1.y, x1.z, x1.w,
                        x2.x, x2.y, x2.z, x2.w, x3.x, x3.y, x3.z, x3.w};
        float sq = 0.f;
        #pragma unroll
        for (int i = 0; i < 16; ++i) { float dd = xv[i] - m; sq += dd * dd; }
        sq += __shfl_xor(sq, 1, 64); sq += __shfl_xor(sq, 2, 64);
        float rs = rsqrtf(sq * (1.f / 64.f) + 1e-5f);
        unsigned short u[16];
        #pragma unroll
        for (int i = 0; i < 16; ++i)
            u[i] = f2bf((xv[i] - m) * rs * lnw[c0 + i] + lnb[c0 + i]);
        int g0 = (t & 3) * 2, g1 = g0 + 1;
        *(bf16x8*)(A1 + g0 * 512 + ((r * 8) ^ ((g0 & 3) * 8))) = *(bf16x8*)&u[0];
        *(bf16x8*)(A1 + g1 * 512 + ((r * 8) ^ ((g1 & 3) * 8))) = *(bf16x8*)&u[8];
    }
    __syncthreads();

    // ---- fc1 (swapped): acc1[ct][rt] ----
    f32x4 acc1[4][4] = {};
    #pragma unroll
    for (int kt = 0; kt < 2; ++kt) {
        {   // stage 16KB chunk of B1img via global_load_lds
            #pragma unroll
            for (int c = 0; c < 4; ++c) {
                int i = c * 256 + t;
                gl_lds16(B1img + (size_t)kt * 8192 + (size_t)i * 8,
                         Bst + (size_t)(c * 256 + (t & ~63)) * 8);
            }
        }
        __syncthreads();
        bf16x8 bfrag[4];
        #pragma unroll
        for (int rt = 0; rt < 4; ++rt)
            bfrag[rt] = *(bf16x8*)(A1 + (kt * 4 + kg) * 512 + (((rt * 16 + li) * 8) ^ (kg * 8)));
        #pragma unroll
        for (int ct = 0; ct < 4; ++ct) {
            bf16x8 af = *(bf16x8*)(Bst + kg * 2048 + (((wid * 64 + ct * 16 + li) ^ kg) * 8));
            #pragma unroll
            for (int rt = 0; rt < 4; ++rt)
                acc1[ct][rt] = __builtin_amdgcn_mfma_f32_16x16x32_bf16(af, bfrag[rt], acc1[ct][rt], 0, 0, 0);
        }
        __syncthreads();
    }

    // ---- bias + relu + bf16, packed b64 writes into Y1 ----
    #pragma unroll
    for (int ct = 0; ct < 4; ++ct) {
        int c0 = wid * 64 + ct * 16 + kg * 4;
        float4 b1 = *(const float4*)(fc1b + c0);
        int g = c0 >> 3;
        #pragma unroll
        for (int rt = 0; rt < 4; ++rt) {
            f32x4 vv = acc1[ct][rt];
            float y0 = fmaxf(vv[0] + b1.x, 0.f), y1v = fmaxf(vv[1] + b1.y, 0.f);
            float y2 = fmaxf(vv[2] + b1.z, 0.f), y3 = fmaxf(vv[3] + b1.w, 0.f);
            unsigned lo = (unsigned)f2bf(y0) | ((unsigned)f2bf(y1v) << 16);
            unsigned hi = (unsigned)f2bf(y2) | ((unsigned)f2bf(y3) << 16);
            int r = rt * 16 + li;
            int off = g * 512 + ((r * 8) ^ ((g & 3) * 8)) + (c0 & 7);
            uint2 pk; pk.x = lo; pk.y = hi;
            *(uint2*)(Y1 + off) = pk;
        }
    }
    __syncthreads();

    // ---- fc2 ----
    f32x4 acc2[4] = {};
    #pragma unroll
    for (int hc = 0; hc < 2; ++hc) {
        {   // stage 16KB chunk of B2img via global_load_lds
            #pragma unroll
            for (int c = 0; c < 4; ++c) {
                int i = c * 256 + t;
                gl_lds16(B2img + (size_t)hc * 8192 + (size_t)i * 8,
                         Bst + (size_t)(c * 256 + (t & ~63)) * 8);
            }
        }
        __syncthreads();
        #pragma unroll
        for (int ktl = 0; ktl < 4; ++ktl) {
            int ktg = hc * 4 + ktl;
            bf16x8 af = *(bf16x8*)(Y1 + (ktg * 4 + kg) * 512 + (((wid * 16 + li) * 8) ^ (kg * 8)));
            #pragma unroll
            for (int nt = 0; nt < 4; ++nt) {
                bf16x8 bf = *(bf16x8*)(Bst + (ktl * 4 + kg) * 512 + (((nt * 16 + li) ^ kg) * 8));
                acc2[nt] = __builtin_amdgcn_mfma_f32_16x16x32_bf16(af, bf, acc2[nt], 0, 0, 0);
            }
        }
        __syncthreads();
    }

    // ---- epilogue: residual add in-place; stash bf16 into A1 ----
    #pragma unroll
    for (int nt = 0; nt < 4; ++nt) {
        int dd = nt * 16 + li;
        float b2 = fc2b[dd];
        #pragma unroll
        for (int q = 0; q < 4; ++q) {
            int r = wid * 16 + kg * 4 + q;
            size_t gp = (p0 + r) * 64 + dd;
            float val = slots[gp] + acc2[nt][q] + b2;
            slots[gp] = val;
            A1[r * 64 + dd] = f2bf(val);
        }
    }
    if (write_hg) {
        __syncthreads();
        #pragma unroll
        for (int c2 = 0; c2 < 2; ++c2) {
            int n = c2 * 256 + t;           // 0..511 = (h*8+g)*8 + eloc
            int eloc = n & 7;
            int hg8 = n >> 3;
            int hh = hg8 >> 3, g = hg8 & 7;
            int r = eloc * 8 + hh;
            bf16x8 v = *(bf16x8*)(A1 + r * 64 + g * 8);
            int k = hh * 64 + g * 8;
            int tt = k >> 5, kgg = (k >> 3) & 3;
            size_t e = (size_t)blockIdx.x * 8 + eloc;
            *(bf16x8*)(h_g + ((size_t)(tt * 4 + kgg) * E + e) * 8) = v;
        }
    }
}

extern "C" void kernel_launch(void* const* d_in, const int* in_sizes, int n_in,
                              void* d_out, int out_size, void* d_ws, size_t ws_size,
                              hipStream_t stream) {
    const float* x     = (const float*)d_in[0];
    const int*   eidx  = (const int*)d_in[1];
    const float* nd    = (const float*)d_in[3];
    const float* mu    = (const float*)d_in[4];
    const float* lsig  = (const float*)d_in[5];
    const float* atten = (const float*)d_in[6];
    const float* ln_sw = (const float*)d_in[7];
    const float* ln_sb = (const float*)d_in[8];
    const float* ln_mw = (const float*)d_in[9];
    const float* ln_mb = (const float*)d_in[10];
    const float* Wq    = (const float*)d_in[11];
    const float* Wk    = (const float*)d_in[12];
    const float* w_ih  = (const float*)d_in[13];
    const float* w_hh  = (const float*)d_in[14];
    const float* b_ih  = (const float*)d_in[15];
    const float* b_hh  = (const float*)d_in[16];
    const float* fc1w  = (const float*)d_in[17];
    const float* fc1b  = (const float*)d_in[18];
    const float* fc2w  = (const float*)d_in[19];
    const float* fc2b  = (const float*)d_in[20];

    float* out = (float*)d_out;
    char* ws = (char*)d_ws;
    size_t off = 0;
    auto alloc = [&](size_t nbytes) {
        void* p = ws + off;
        off += (nbytes + 255) & ~(size_t)255;
        return p;
    };
    float*          slotsA = (float*)alloc((size_t)E * HD * 4);
    float*          kbuf   = (float*)alloc((size_t)E * 64 * 4);
    float*          alpha  = (float*)alloc((size_t)E * 8 * 4);
    unsigned*       segmax = (unsigned*)alloc((size_t)Nn * 8 * 4);
    float*          segsum = (float*)alloc((size_t)Nn * 8 * 4);
    float*          vbuf   = (float*)alloc(512 * 4);
    unsigned short* B1img  = (unsigned short*)alloc(16384 * 2);
    unsigned short* B2img  = (unsigned short*)alloc(16384 * 2);
    unsigned short* wb     = (unsigned short*)alloc((size_t)1572864 * 2);
    unsigned short* u_g    = (unsigned short*)alloc((size_t)E * HD * 2);
    unsigned short* h_g    = (unsigned short*)alloc((size_t)E * HD * 2);

    prep_v<<<1, 512, 0, stream>>>(atten, Wq, vbuf);
    prep_mlp<<<128, 256, 0, stream>>>(fc1w, fc2w, B1img, B2img);
    wprep<<<6144, 256, 0, stream>>>(w_ih, w_hh, wb);
    compute_k<<<4096, 256, 0, stream>>>(x, Wk, kbuf);
    init_slots<<<2048, 256, 0, stream>>>(nd, mu, lsig, slotsA, h_g);

    float* cur = slotsA;
    float* nxt = out;
    for (int it = 0; it < 3; ++it) {
        seg_init<<<512, 256, 0, stream>>>(segmax, segsum);
        alpha_ln<<<E * 8 / 4, 256, 0, stream>>>(cur, vbuf, ln_sw, ln_sb, eidx, alpha, segmax);
        exp_sum<<<E * 8 / 256, 256, 0, stream>>>(eidx, segmax, alpha, segsum);
        prep_u<<<E / 256, 256, 0, stream>>>(kbuf, alpha, segsum, eidx, u_g);
        gru_mfma<<<16384, 256, 0, stream>>>(cur, u_g, h_g, wb, b_ih, b_hh, nxt);
        mlp_mfma<<<32768, 256, 0, stream>>>(nxt, B1img, B2img, ln_mw, ln_mb, fc1b, fc2b,
                                            h_g, (it < 2) ? 1 : 0);
        float* tmp = cur; cur = nxt; nxt = tmp;
    }
    (void)in_sizes; (void)n_in; (void)out_size; (void)ws_size;
}

// Round 5
// 7723.792 us; speedup vs baseline: 57.9784x; 1.0934x over previous
//
#include <hip/hip_runtime.h>
#include <math.h>

#define E 262144
#define Nn 16384
#define H 8
#define D 64
#define HD 512
#define HID 256

typedef float f32x4 __attribute__((ext_vector_type(4)));
typedef short bf16x8 __attribute__((ext_vector_type(8)));

__device__ __forceinline__ float wave_sum(float v) {
    #pragma unroll
    for (int m = 1; m < 64; m <<= 1) v += __shfl_xor(v, m, 64);
    return v;
}

__device__ __forceinline__ unsigned short f2bf(float f) {
    unsigned u = __float_as_uint(f);
    return (unsigned short)((u + 0x7fffu + ((u >> 16) & 1u)) >> 16);
}

__device__ __forceinline__ void gl_lds16(const void* g, void* l) {
    __builtin_amdgcn_global_load_lds(
        (const __attribute__((address_space(1))) void*)g,
        (__attribute__((address_space(3))) void*)l, 16, 0, 0);
}

// v[h][j] = sum_d atten[h][d] * Wq[d][j]
__global__ void prep_v(const float* __restrict__ atten, const float* __restrict__ Wq,
                       float* __restrict__ v) {
    int t = threadIdx.x;            // 512 threads
    int h = t >> 6, j = t & 63;
    float a = 0.f;
    #pragma unroll 8
    for (int d = 0; d < 64; ++d) a += atten[h * 64 + d] * Wq[d * 64 + j];
    v[h * 64 + j] = a;
}

// MLP weight images (bf16, MFMA-frag layout, kg-XOR bank swizzle baked in)
__global__ void prep_mlp(const float* __restrict__ fc1w, const float* __restrict__ fc2w,
                         unsigned short* __restrict__ B1img, unsigned short* __restrict__ B2img) {
    int i = blockIdx.x * 256 + threadIdx.x;   // 32768 total
    if (i < 16384) {
        int j = i & 7, g = i >> 3;
        int cs = g & 255, kgkt = g >> 8;
        int kg = kgkt & 3, kt = kgkt >> 2;
        int c = cs ^ kg;
        int k = kt * 32 + kg * 8 + j;
        B1img[i] = f2bf(fc1w[c * 64 + k]);
    } else {
        int i2 = i - 16384;
        int j = i2 & 7, g = i2 >> 3;
        int ds = g & 63, kgkt = g >> 6;
        int kg = kgkt & 3, kt = kgkt >> 2;
        int dd = ds ^ kg;
        int c = kt * 32 + kg * 8 + j;
        B2img[i2] = f2bf(fc2w[dd * 256 + c]);
    }
}

// GRU weights bf16 image for BN=32:
// wb[cb(16)][t(16)][m(6)][kg(4)][cs(32)][j(8)] = w[(m%3)*512 + cb*32 + (cs^kg)][t*32+kg*8+j]
__global__ void wprep(const float* __restrict__ w_ih, const float* __restrict__ w_hh,
                      unsigned short* __restrict__ wb) {
    int o = blockIdx.x * 256 + threadIdx.x;   // 1,572,864 total
    int slice = o / 6144;
    int w = o - slice * 6144;
    int t = slice & 15, cb = slice >> 4;
    int j = w & 7;
    int cs = (w >> 3) & 31;
    int kgm = w >> 8;
    int kg = kgm & 3, m = kgm >> 2;
    const float* wm = (m < 3) ? w_ih : w_hh;
    int row = (m % 3) * 512 + cb * 32 + (cs ^ kg);
    int k = t * 32 + kg * 8 + j;
    wb[o] = f2bf(wm[(size_t)row * 512 + k]);
}

// k[e][d] = 0.125 * sum_j x[e][j] * Wk[d][j]
__global__ __launch_bounds__(256) void compute_k(const float* __restrict__ x,
                                                 const float* __restrict__ Wk,
                                                 float* __restrict__ kbuf) {
    __shared__ float sWk[64][130];
    int t = threadIdx.x;
    for (int i = t; i < 64 * 128; i += 256) sWk[i >> 7][i & 127] = Wk[i];
    __syncthreads();
    int lane = t & 63, w = t >> 6;
    for (int e = blockIdx.x * 4 + w; e < E; e += gridDim.x * 4) {
        const float* xr = x + (size_t)e * 128;
        float acc = 0.f;
        #pragma unroll 8
        for (int j = 0; j < 128; ++j) acc += xr[j] * sWk[lane][j];
        kbuf[(size_t)e * 64 + lane] = acc * 0.125f;
    }
}

// slots = mu + exp(log_sigma) * norm_dist ; also emit bf16 h_g image
__global__ void init_slots(const float* __restrict__ nd, const float* __restrict__ mu,
                           const float* __restrict__ lsig, float* __restrict__ out,
                           unsigned short* __restrict__ h_g) {
    __shared__ float sMu[64], sSig[64];
    if (threadIdx.x < 64) {
        sMu[threadIdx.x]  = mu[threadIdx.x];
        sSig[threadIdx.x] = __expf(lsig[threadIdx.x]);
    }
    __syncthreads();
    size_t n4 = (size_t)E * HD / 4;
    size_t stride = (size_t)gridDim.x * blockDim.x;
    for (size_t i = (size_t)blockIdx.x * blockDim.x + threadIdx.x; i < n4; i += stride) {
        float4 v = ((const float4*)nd)[i];
        size_t flat = i * 4;
        int d0 = (int)(flat & 63);
        v.x = sMu[d0]     + sSig[d0]     * v.x;
        v.y = sMu[d0 + 1] + sSig[d0 + 1] * v.y;
        v.z = sMu[d0 + 2] + sSig[d0 + 2] * v.z;
        v.w = sMu[d0 + 3] + sSig[d0 + 3] * v.w;
        ((float4*)out)[i] = v;
        int e = (int)(flat >> 9);
        int k = (int)(flat & 511);
        int tt = k >> 5, kgg = (k >> 3) & 3, jo = k & 7;  // jo in {0,4}
        uint2 pk;
        pk.x = (unsigned)f2bf(v.x) | ((unsigned)f2bf(v.y) << 16);
        pk.y = (unsigned)f2bf(v.z) | ((unsigned)f2bf(v.w) << 16);
        *(uint2*)(h_g + ((size_t)(tt * 4 + kgg) * E + e) * 8 + jo) = pk;
    }
}

__global__ void seg_init(unsigned* __restrict__ segmax, float* __restrict__ segsum) {
    int i = blockIdx.x * 256 + threadIdx.x;
    if (i < Nn * H) { segmax[i] = 0u; segsum[i] = 0.f; }
}

// one wave per (e,h): LN(slots row) -> dot v_h -> leaky_relu -> alpha ; atomicMax into segmax
__global__ __launch_bounds__(256) void alpha_ln(const float* __restrict__ cur,
                                                const float* __restrict__ v,
                                                const float* __restrict__ lnw,
                                                const float* __restrict__ lnb,
                                                const int* __restrict__ eidx,
                                                float* __restrict__ alpha,
                                                unsigned* __restrict__ segmax) {
    int lane = threadIdx.x & 63, w = threadIdx.x >> 6;
    size_t p = (size_t)blockIdx.x * 4 + w;          // grid = E*H/4 exactly
    float x = cur[p * 64 + lane];
    float m = wave_sum(x) * (1.f / 64.f);
    float d = x - m;
    float var = wave_sum(d * d) * (1.f / 64.f);
    float rs = rsqrtf(var + 1e-5f);
    float ln = d * rs * lnw[lane] + lnb[lane];
    int h = (int)(p & 7);
    float dot = wave_sum(ln * v[h * 64 + lane]) * 0.125f;
    float a = dot >= 0.f ? dot : 0.2f * dot;
    if (lane == 0) {
        alpha[p] = a;
        int e = (int)(p >> 3);
        int id = eidx[e];
        unsigned b = __float_as_uint(a);
        unsigned enc = (b & 0x80000000u) ? ~b : (b | 0x80000000u);
        atomicMax(&segmax[id * 8 + h], enc);
    }
}

__global__ void exp_sum(const int* __restrict__ eidx, const unsigned* __restrict__ segmax,
                        float* __restrict__ alpha, float* __restrict__ segsum) {
    size_t p = (size_t)blockIdx.x * 256 + threadIdx.x;
    int e = (int)(p >> 3), h = (int)(p & 7);
    int id = eidx[e];
    unsigned u = segmax[id * 8 + h];
    float m = __uint_as_float((u & 0x80000000u) ? (u & 0x7fffffffu) : ~u);
    float val = __expf(alpha[p] - m);
    alpha[p] = val;
    atomicAdd(&segsum[id * 8 + h], val);
}

// normalize alpha + build u_g = bf16((k*alpha)) in [t][kg][E][8] layout. thread per edge.
__global__ __launch_bounds__(256) void prep_u(const float* __restrict__ kbuf,
                                              const float* __restrict__ alpha,
                                              const float* __restrict__ segsum,
                                              const int* __restrict__ eidx,
                                              unsigned short* __restrict__ u_g) {
    int e = blockIdx.x * 256 + threadIdx.x;
    int id = eidx[e];
    float a[8];
    #pragma unroll
    for (int h = 0; h < 8; ++h)
        a[h] = alpha[(size_t)e * 8 + h] / (segsum[id * 8 + h] + 1e-16f);
    float4 kv[16];
    const float4* kr = (const float4*)(kbuf + (size_t)e * 64);
    #pragma unroll
    for (int q = 0; q < 16; ++q) kv[q] = kr[q];
    const float* kf = (const float*)kv;
    #pragma unroll
    for (int tt = 0; tt < 16; ++tt) {
        float ah = a[tt >> 1];
        #pragma unroll
        for (int kg = 0; kg < 4; ++kg) {
            int dbase = (tt & 1) * 32 + kg * 8;
            bf16x8 v;
            #pragma unroll
            for (int j = 0; j < 8; ++j) v[j] = (short)f2bf(kf[dbase + j] * ah);
            *(bf16x8*)(u_g + ((size_t)(tt * 4 + kg) * E + e) * 8) = v;
        }
    }
}

// ---------------- MFMA GRU : BM=256 x BN=32, BK=32, dbuf-A + counted vmcnt ----------------
// LDS entries (16B each): bufA[p] at p*2048 (u [0,1024) = [kg][el], h [1024,2048));
// W at 4096 + [0,768). Total 4864 entries = 76 KB (dynamic LDS).
__global__ __launch_bounds__(256, 2) void gru_mfma(
    const float* __restrict__ cur, const unsigned short* __restrict__ u_g,
    const unsigned short* __restrict__ h_g, const unsigned short* __restrict__ wb,
    const float* __restrict__ b_ih, const float* __restrict__ b_hh,
    float* __restrict__ nxt) {

    extern __shared__ unsigned short lds[];

    int bid = blockIdx.x;
    int lbid = (bid & 7) * 2048 + (bid >> 3);   // XCD-contiguous chunks (16384 % 8 == 0)
    int eb = lbid >> 4, cb = lbid & 15;
    int e0 = eb * 256;
    int t = threadIdx.x;
    int lane = t & 63, wid = t >> 6;
    int li = lane & 15, kg = lane >> 4;
    int EB = wid * 64;

    const unsigned short* wsl = wb + (size_t)(cb * 16) * 6144;

    f32x4 acc[4][4][2] = {};   // [plane][m][f]

    auto stage_a = [&](int ts, int p) {
        #pragma unroll
        for (int c = 0; c < 8; ++c) {
            int i = c * 256 + t;    // entry in [0,2048); per wave: kgg uniform, el contiguous
            unsigned short* lp = lds + (size_t)(p * 2048 + c * 256 + (t & ~63)) * 8;
            const unsigned short* gp;
            if (c < 4) {
                int kgg = i >> 8, el = i & 255;
                gp = u_g + ((size_t)(ts * 4 + kgg) * E + (e0 + el)) * 8;
            } else {
                int i2 = i - 1024; int kgg = i2 >> 8, el = i2 & 255;
                gp = h_g + ((size_t)(ts * 4 + kgg) * E + (e0 + el)) * 8;
            }
            gl_lds16(gp, lp);
        }
    };
    auto stage_w = [&](int ts) {
        #pragma unroll
        for (int c = 0; c < 3; ++c) {
            int i = c * 256 + t;    // entry in [0,768)
            unsigned short* lp = lds + (size_t)(4096 + c * 256 + (t & ~63)) * 8;
            const unsigned short* gp = wsl + ((size_t)ts * 768 + i) * 8;
            gl_lds16(gp, lp);
        }
    };
    auto compute = [&](int p) {
        bf16x8 au[4], ah[4];
        #pragma unroll
        for (int m = 0; m < 4; ++m) {
            int ea = p * 2048 + kg * 256 + EB + m * 16 + li;
            au[m] = *(bf16x8*)(lds + (size_t)ea * 8);
            ah[m] = *(bf16x8*)(lds + (size_t)(1024 + ea) * 8);
        }
        const unsigned short* W = lds + (size_t)4096 * 8;
        #pragma unroll
        for (int f = 0; f < 2; ++f) {
            int cs = (f * 16 + li) ^ kg;
            bf16x8 bir = *(bf16x8*)(W + ((size_t)(0 * 4 + kg) * 32 + cs) * 8);
            bf16x8 biz = *(bf16x8*)(W + ((size_t)(1 * 4 + kg) * 32 + cs) * 8);
            bf16x8 bin = *(bf16x8*)(W + ((size_t)(2 * 4 + kg) * 32 + cs) * 8);
            bf16x8 bhr = *(bf16x8*)(W + ((size_t)(3 * 4 + kg) * 32 + cs) * 8);
            bf16x8 bhz = *(bf16x8*)(W + ((size_t)(4 * 4 + kg) * 32 + cs) * 8);
            bf16x8 bhn = *(bf16x8*)(W + ((size_t)(5 * 4 + kg) * 32 + cs) * 8);
            #pragma unroll
            for (int m = 0; m < 4; ++m) {
                acc[0][m][f] = __builtin_amdgcn_mfma_f32_16x16x32_bf16(au[m], bir, acc[0][m][f], 0, 0, 0);
                acc[0][m][f] = __builtin_amdgcn_mfma_f32_16x16x32_bf16(ah[m], bhr, acc[0][m][f], 0, 0, 0);
                acc[1][m][f] = __builtin_amdgcn_mfma_f32_16x16x32_bf16(au[m], biz, acc[1][m][f], 0, 0, 0);
                acc[1][m][f] = __builtin_amdgcn_mfma_f32_16x16x32_bf16(ah[m], bhz, acc[1][m][f], 0, 0, 0);
                acc[2][m][f] = __builtin_amdgcn_mfma_f32_16x16x32_bf16(au[m], bin, acc[2][m][f], 0, 0, 0);
                acc[3][m][f] = __builtin_amdgcn_mfma_f32_16x16x32_bf16(ah[m], bhn, acc[3][m][f], 0, 0, 0);
            }
        }
    };

    // prologue: tile 0 in flight (11 ops/thread)
    stage_a(0, 0);
    stage_w(0);

    for (int ts = 0; ts < 15; ++ts) {
        int p = ts & 1;
        stage_a(ts + 1, p ^ 1);                     // +8 in flight
        // FIFO: A(ts)[8], W(ts)[3], A(ts+1)[8] -> wait for first 11
        asm volatile("s_waitcnt vmcnt(8)" ::: "memory");
        __builtin_amdgcn_s_barrier();
        compute(p);
        asm volatile("" ::: "memory");
        __builtin_amdgcn_s_barrier();               // all waves done with W(ts) + bufA[p]
        stage_w(ts + 1);                            // +3 in flight
    }
    asm volatile("s_waitcnt vmcnt(0)" ::: "memory");
    __builtin_amdgcn_s_barrier();
    compute(1);                                     // ts = 15

    // epilogue: gates f32
    #pragma unroll
    for (int f = 0; f < 2; ++f) {
        int c = cb * 32 + f * 16 + li;
        float br = b_ih[c] + b_hh[c];
        float bz = b_ih[c + 512] + b_hh[c + 512];
        float bi = b_ih[c + 1024];
        float bh = b_hh[c + 1024];
        #pragma unroll
        for (int m = 0; m < 4; ++m) {
            #pragma unroll
            for (int q = 0; q < 4; ++q) {
                size_t ge = (size_t)(e0 + EB + m * 16 + kg * 4 + q);
                float r = 1.f / (1.f + __expf(-(acc[0][m][f][q] + br)));
                float z = 1.f / (1.f + __expf(-(acc[1][m][f][q] + bz)));
                float n = tanhf(acc[2][m][f][q] + bi + r * (acc[3][m][f][q] + bh));
                float hp = cur[ge * 512 + c];
                nxt[ge * 512 + c] = (1.f - z) * n + z * hp;
            }
        }
    }
}

// ---------------- MFMA MLP (fused LN + fc1 + relu + fc2 + residual + h_g emit) ----------------
__global__ __launch_bounds__(256, 2) void mlp_mfma(
    float* __restrict__ slots,
    const unsigned short* __restrict__ B1img, const unsigned short* __restrict__ B2img,
    const float* __restrict__ lnw, const float* __restrict__ lnb,
    const float* __restrict__ fc1b, const float* __restrict__ fc2b,
    unsigned short* __restrict__ h_g, int write_hg) {

    __shared__ unsigned short A1[4096];    // frag tile, later reused as [row64][d64] bf16
    __shared__ unsigned short Bst[8192];   // weight staging chunk 16 KB
    __shared__ unsigned short Y1[16384];   // 32 KB

    int t = threadIdx.x;
    int lane = t & 63, wid = t >> 6;
    int li = lane & 15, kg = lane >> 4;
    size_t p0 = (size_t)blockIdx.x * 64;

    // ---- phase 0: load rows, LN (4 threads/row), bf16 A1 tile ----
    {
        int r = t >> 2, c0 = (t & 3) * 16;
        const float* rowp = slots + (p0 + r) * 64 + c0;
        float4 x0 = ((const float4*)rowp)[0];
        float4 x1 = ((const float4*)rowp)[1];
        float4 x2 = ((const float4*)rowp)[2];
        float4 x3 = ((const float4*)rowp)[3];
        float s = x0.x + x0.y + x0.z + x0.w + x1.x + x1.y + x1.z + x1.w
                + x2.x + x2.y + x2.z + x2.w + x3.x + x3.y + x3.z + x3.w;
        s += __shfl_xor(s, 1, 64); s += __shfl_xor(s, 2, 64);
        float m = s * (1.f / 64.f);
        float xv[16] = {x0.x, x0.y, x0.z, x0.w, x1.x, x1.y, x1.z, x1.w,
                        x2.x, x2.y, x2.z, x2.w, x3.x, x3.y, x3.z, x3.w};
        float sq = 0.f;
        #pragma unroll
        for (int i = 0; i < 16; ++i) { float dd = xv[i] - m; sq += dd * dd; }
        sq += __shfl_xor(sq, 1, 64); sq += __shfl_xor(sq, 2, 64);
        float rs = rsqrtf(sq * (1.f / 64.f) + 1e-5f);
        unsigned short u[16];
        #pragma unroll
        for (int i = 0; i < 16; ++i)
            u[i] = f2bf((xv[i] - m) * rs * lnw[c0 + i] + lnb[c0 + i]);
        int g0 = (t & 3) * 2, g1 = g0 + 1;
        *(bf16x8*)(A1 + g0 * 512 + ((r * 8) ^ ((g0 & 3) * 8))) = *(bf16x8*)&u[0];
        *(bf16x8*)(A1 + g1 * 512 + ((r * 8) ^ ((g1 & 3) * 8))) = *(bf16x8*)&u[8];
    }
    __syncthreads();

    // ---- fc1 (swapped): acc1[ct][rt] ----
    f32x4 acc1[4][4] = {};
    #pragma unroll
    for (int kt = 0; kt < 2; ++kt) {
        {   // stage 16KB chunk of B1img via global_load_lds
            #pragma unroll
            for (int c = 0; c < 4; ++c) {
                int i = c * 256 + t;
                gl_lds16(B1img + (size_t)kt * 8192 + (size_t)i * 8,
                         Bst + (size_t)(c * 256 + (t & ~63)) * 8);
            }
        }
        __syncthreads();
        bf16x8 bfrag[4];
        #pragma unroll
        for (int rt = 0; rt < 4; ++rt)
            bfrag[rt] = *(bf16x8*)(A1 + (kt * 4 + kg) * 512 + (((rt * 16 + li) * 8) ^ (kg * 8)));
        #pragma unroll
        for (int ct = 0; ct < 4; ++ct) {
            bf16x8 af = *(bf16x8*)(Bst + kg * 2048 + (((wid * 64 + ct * 16 + li) ^ kg) * 8));
            #pragma unroll
            for (int rt = 0; rt < 4; ++rt)
                acc1[ct][rt] = __builtin_amdgcn_mfma_f32_16x16x32_bf16(af, bfrag[rt], acc1[ct][rt], 0, 0, 0);
        }
        __syncthreads();
    }

    // ---- bias + relu + bf16, packed b64 writes into Y1 ----
    #pragma unroll
    for (int ct = 0; ct < 4; ++ct) {
        int c0 = wid * 64 + ct * 16 + kg * 4;
        float4 b1 = *(const float4*)(fc1b + c0);
        int g = c0 >> 3;
        #pragma unroll
        for (int rt = 0; rt < 4; ++rt) {
            f32x4 vv = acc1[ct][rt];
            float y0 = fmaxf(vv[0] + b1.x, 0.f), y1v = fmaxf(vv[1] + b1.y, 0.f);
            float y2 = fmaxf(vv[2] + b1.z, 0.f), y3 = fmaxf(vv[3] + b1.w, 0.f);
            unsigned lo = (unsigned)f2bf(y0) | ((unsigned)f2bf(y1v) << 16);
            unsigned hi = (unsigned)f2bf(y2) | ((unsigned)f2bf(y3) << 16);
            int r = rt * 16 + li;
            int off = g * 512 + ((r * 8) ^ ((g & 3) * 8)) + (c0 & 7);
            uint2 pk; pk.x = lo; pk.y = hi;
            *(uint2*)(Y1 + off) = pk;
        }
    }
    __syncthreads();

    // ---- fc2 ----
    f32x4 acc2[4] = {};
    #pragma unroll
    for (int hc = 0; hc < 2; ++hc) {
        {   // stage 16KB chunk of B2img via global_load_lds
            #pragma unroll
            for (int c = 0; c < 4; ++c) {
                int i = c * 256 + t;
                gl_lds16(B2img + (size_t)hc * 8192 + (size_t)i * 8,
                         Bst + (size_t)(c * 256 + (t & ~63)) * 8);
            }
        }
        __syncthreads();
        #pragma unroll
        for (int ktl = 0; ktl < 4; ++ktl) {
            int ktg = hc * 4 + ktl;
            bf16x8 af = *(bf16x8*)(Y1 + (ktg * 4 + kg) * 512 + (((wid * 16 + li) * 8) ^ (kg * 8)));
            #pragma unroll
            for (int nt = 0; nt < 4; ++nt) {
                bf16x8 bf = *(bf16x8*)(Bst + (ktl * 4 + kg) * 512 + (((nt * 16 + li) ^ kg) * 8));
                acc2[nt] = __builtin_amdgcn_mfma_f32_16x16x32_bf16(af, bf, acc2[nt], 0, 0, 0);
            }
        }
        __syncthreads();
    }

    // ---- epilogue: residual add in-place; stash bf16 into A1 ----
    #pragma unroll
    for (int nt = 0; nt < 4; ++nt) {
        int dd = nt * 16 + li;
        float b2 = fc2b[dd];
        #pragma unroll
        for (int q = 0; q < 4; ++q) {
            int r = wid * 16 + kg * 4 + q;
            size_t gp = (p0 + r) * 64 + dd;
            float val = slots[gp] + acc2[nt][q] + b2;
            slots[gp] = val;
            A1[r * 64 + dd] = f2bf(val);
        }
    }
    if (write_hg) {
        __syncthreads();
        #pragma unroll
        for (int c2 = 0; c2 < 2; ++c2) {
            int n = c2 * 256 + t;           // 0..511 = (h*8+g)*8 + eloc
            int eloc = n & 7;
            int hg8 = n >> 3;
            int hh = hg8 >> 3, g = hg8 & 7;
            int r = eloc * 8 + hh;
            bf16x8 v = *(bf16x8*)(A1 + r * 64 + g * 8);
            int k = hh * 64 + g * 8;
            int tt = k >> 5, kgg = (k >> 3) & 3;
            size_t e = (size_t)blockIdx.x * 8 + eloc;
            *(bf16x8*)(h_g + ((size_t)(tt * 4 + kgg) * E + e) * 8) = v;
        }
    }
}

extern "C" void kernel_launch(void* const* d_in, const int* in_sizes, int n_in,
                              void* d_out, int out_size, void* d_ws, size_t ws_size,
                              hipStream_t stream) {
    const float* x     = (const float*)d_in[0];
    const int*   eidx  = (const int*)d_in[1];
    const float* nd    = (const float*)d_in[3];
    const float* mu    = (const float*)d_in[4];
    const float* lsig  = (const float*)d_in[5];
    const float* atten = (const float*)d_in[6];
    const float* ln_sw = (const float*)d_in[7];
    const float* ln_sb = (const float*)d_in[8];
    const float* ln_mw = (const float*)d_in[9];
    const float* ln_mb = (const float*)d_in[10];
    const float* Wq    = (const float*)d_in[11];
    const float* Wk    = (const float*)d_in[12];
    const float* w_ih  = (const float*)d_in[13];
    const float* w_hh  = (const float*)d_in[14];
    const float* b_ih  = (const float*)d_in[15];
    const float* b_hh  = (const float*)d_in[16];
    const float* fc1w  = (const float*)d_in[17];
    const float* fc1b  = (const float*)d_in[18];
    const float* fc2w  = (const float*)d_in[19];
    const float* fc2b  = (const float*)d_in[20];

    float* out = (float*)d_out;
    char* ws = (char*)d_ws;
    size_t off = 0;
    auto alloc = [&](size_t nbytes) {
        void* p = ws + off;
        off += (nbytes + 255) & ~(size_t)255;
        return p;
    };
    float*          slotsA = (float*)alloc((size_t)E * HD * 4);
    float*          kbuf   = (float*)alloc((size_t)E * 64 * 4);
    float*          alpha  = (float*)alloc((size_t)E * 8 * 4);
    unsigned*       segmax = (unsigned*)alloc((size_t)Nn * 8 * 4);
    float*          segsum = (float*)alloc((size_t)Nn * 8 * 4);
    float*          vbuf   = (float*)alloc(512 * 4);
    unsigned short* B1img  = (unsigned short*)alloc(16384 * 2);
    unsigned short* B2img  = (unsigned short*)alloc(16384 * 2);
    unsigned short* wb     = (unsigned short*)alloc((size_t)1572864 * 2);
    unsigned short* u_g    = (unsigned short*)alloc((size_t)E * HD * 2);
    unsigned short* h_g    = (unsigned short*)alloc((size_t)E * HD * 2);

    const int GRU_LDS_BYTES = 4864 * 16;   // 76 KB dynamic LDS
    hipFuncSetAttribute((const void*)gru_mfma,
                        hipFuncAttributeMaxDynamicSharedMemorySize, GRU_LDS_BYTES);

    prep_v<<<1, 512, 0, stream>>>(atten, Wq, vbuf);
    prep_mlp<<<128, 256, 0, stream>>>(fc1w, fc2w, B1img, B2img);
    wprep<<<6144, 256, 0, stream>>>(w_ih, w_hh, wb);
    compute_k<<<4096, 256, 0, stream>>>(x, Wk, kbuf);
    init_slots<<<2048, 256, 0, stream>>>(nd, mu, lsig, slotsA, h_g);

    float* cur = slotsA;
    float* nxt = out;
    for (int it = 0; it < 3; ++it) {
        seg_init<<<512, 256, 0, stream>>>(segmax, segsum);
        alpha_ln<<<E * 8 / 4, 256, 0, stream>>>(cur, vbuf, ln_sw, ln_sb, eidx, alpha, segmax);
        exp_sum<<<E * 8 / 256, 256, 0, stream>>>(eidx, segmax, alpha, segsum);
        prep_u<<<E / 256, 256, 0, stream>>>(kbuf, alpha, segsum, eidx, u_g);
        gru_mfma<<<16384, 256, GRU_LDS_BYTES, stream>>>(cur, u_g, h_g, wb, b_ih, b_hh, nxt);
        mlp_mfma<<<32768, 256, 0, stream>>>(nxt, B1img, B2img, ln_mw, ln_mb, fc1b, fc2b,
                                            h_g, (it < 2) ? 1 : 0);
        float* tmp = cur; cur = nxt; nxt = tmp;
    }
    (void)in_sizes; (void)n_in; (void)out_size; (void)ws_size;
}